// Round 3
// baseline (496.485 us; speedup 1.0000x reference)
//
#include <hip/hip_runtime.h>
#include <hip/hip_bf16.h>
#include <math.h>

#define BN 4096
#define LH 200
#define LFB 100
#define ED 64
#define PD 32
#define HD 32
#define NP 3168   // P + PNET = 32 + 3136

// ws layout (floats)
#define WS_FUE 0                          // final_user_embed B*64
#define WS_FIE (WS_FUE + BN*ED)           // final_item_embed B*64
#define WS_PIN (WS_FIE + BN*ED)           // prompt_input B*64
#define WS_TP  (WS_PIN + BN*ED)           // total_prompt B*3168
#define WS_PPE (WS_TP + (size_t)BN*NP)    // pos_pe B*32

__device__ __forceinline__ unsigned int f2bf_pack(float x, float y) {
    unsigned int ux = __float_as_uint(x);
    unsigned int uy = __float_as_uint(y);
    unsigned int bx = (ux + 0x7fffu + ((ux >> 16) & 1u)) >> 16;
    unsigned int by = (uy + 0x7fffu + ((uy >> 16) & 1u)) >> 16;
    return (by << 16) | (bx & 0xffffu);
}

// ---------------------------------------------------------------------------
// Kernel 1: gathers + attention + pooling.  grid=B, block=256.
// Single staging pass: score computed in fp32 while row streams through regs;
// row stored bf16-packed in LDS for the pooling pass (no second gather).
// hist2 layout: word (l*33 + k/2) -> banks (l + k/2) % 32 : conflict-free.
// ---------------------------------------------------------------------------
#define HS 33
__global__ __launch_bounds__(256, 4) void k1_gather_attn(
    const float* __restrict__ item_emb, const float* __restrict__ user_emb,
    const float* __restrict__ W_if, const float* __restrict__ b_if,
    const float* __restrict__ W_uf, const float* __restrict__ b_uf,
    const float* __restrict__ item_features, const float* __restrict__ user_features,
    const int* __restrict__ user_id, const int* __restrict__ target_item_id,
    const int* __restrict__ hist_id, const int* __restrict__ hist_len,
    const int* __restrict__ pos_fb, const int* __restrict__ pos_mask,
    float* __restrict__ FUE, float* __restrict__ FIE, float* __restrict__ PIN)
{
    const int b = blockIdx.x;
    const int t = threadIdx.x;
    const int w = t >> 6;
    const int lane = t & 63;

    __shared__ __align__(16) float tgt[64];
    __shared__ float feats[256];
    __shared__ float ufe[64];
    __shared__ float scoreS[256];          // raw scores, then attn
    __shared__ float wred[8];
    __shared__ float part[256];
    __shared__ float part2[256];
    __shared__ float cntw[4];
    __shared__ int   hids[200];
    __shared__ unsigned int hist2[200*HS]; // bf16x2 packed rows

    if (t < 200) hids[t] = hist_id[(size_t)b*LH + t];
    feats[t] = (t < 128) ? item_features[(size_t)b*128 + t]
                         : user_features[(size_t)b*128 + (t-128)];
    if (t < 64) tgt[t] = item_emb[(size_t)target_item_id[b]*64 + t];
    __syncthreads();

    // ---- staging + in-flight scores: wave w owns rows [w*50, w*50+50) ----
    const int kk = lane & 31;          // float2 index within row
    const int hf = lane >> 5;          // which of the 2 rows this iter
    const float2 tf = ((const float2*)tgt)[kk];

    #pragma unroll 5
    for (int i = 0; i < 25; i++) {
        const int l = w*50 + i*2 + hf;
        const int id = hids[l];
        const float2 v = ((const float2*)(item_emb + (size_t)id*64))[kk];
        float sp = v.x*tf.x + v.y*tf.y;
        sp += __shfl_xor(sp, 1, 64);
        sp += __shfl_xor(sp, 2, 64);
        sp += __shfl_xor(sp, 4, 64);
        sp += __shfl_xor(sp, 8, 64);
        sp += __shfl_xor(sp, 16, 64);
        hist2[l*HS + kk] = f2bf_pack(v.x, v.y);
        if (kk == 0) scoreS[l] = sp * 0.125f;
    }

    // ---- pos-feedback masked mean (direct gather, overlaps staging) ----
    {
        float acc = 0.f, cnt = 0.f;
        const int l0 = w * 25;
        const int* pid = pos_fb + (size_t)b*LFB;
        const int* pmk = pos_mask + (size_t)b*LFB;
        for (int g = 0; g < 5; g++) {
            const int base = l0 + g*5;
            int m0 = pmk[base+0], m1 = pmk[base+1], m2 = pmk[base+2],
                m3 = pmk[base+3], m4 = pmk[base+4];
            int i0 = pid[base+0], i1 = pid[base+1], i2 = pid[base+2],
                i3 = pid[base+3], i4 = pid[base+4];
            float v0 = item_emb[(size_t)i0*64 + lane];
            float v1 = item_emb[(size_t)i1*64 + lane];
            float v2 = item_emb[(size_t)i2*64 + lane];
            float v3 = item_emb[(size_t)i3*64 + lane];
            float v4 = item_emb[(size_t)i4*64 + lane];
            float f0 = m0 ? 1.f : 0.f, f1 = m1 ? 1.f : 0.f, f2 = m2 ? 1.f : 0.f,
                  f3 = m3 ? 1.f : 0.f, f4 = m4 ? 1.f : 0.f;
            acc = fmaf(f0, v0, acc); acc = fmaf(f1, v1, acc);
            acc = fmaf(f2, v2, acc); acc = fmaf(f3, v3, acc);
            acc = fmaf(f4, v4, acc);
            cnt += f0 + f1 + f2 + f3 + f4;
        }
        part2[w*64 + lane] = acc;
        if (lane == 0) cntw[w] = cnt;
    }

    // ---- feature embeddings (wave 0: item, wave 1: user) ----
    if (w == 0) {
        float acc = b_if[lane];
        #pragma unroll 4
        for (int k = 0; k < 128; k++) acc = fmaf(feats[k], W_if[k*64 + lane], acc);
        FIE[(size_t)b*64 + lane] = tgt[lane] + 1.f / (1.f + __expf(-acc));
    } else if (w == 1) {
        float acc = b_uf[lane];
        #pragma unroll 4
        for (int k = 0; k < 128; k++) acc = fmaf(feats[128 + k], W_uf[k*64 + lane], acc);
        ufe[lane] = 1.f / (1.f + __expf(-acc));
    }
    __syncthreads();

    // ---- softmax over 200 scores (t<200 owns score t) ----
    const int hl = hist_len[b];
    float sc = (t < 200 && t < hl) ? scoreS[t] : -1e9f;
    float m = sc;
    #pragma unroll
    for (int off = 32; off >= 1; off >>= 1) m = fmaxf(m, __shfl_xor(m, off, 64));
    if (lane == 0) wred[w] = m;
    __syncthreads();
    const float mx = fmaxf(fmaxf(wred[0], wred[1]), fmaxf(wred[2], wred[3]));
    const float ev = __expf(sc - mx);
    float s = ev;
    #pragma unroll
    for (int off = 32; off >= 1; off >>= 1) s += __shfl_xor(s, off, 64);
    if (lane == 0) wred[4 + w] = s;
    __syncthreads();
    const float S = wred[4] + wred[5] + wred[6] + wred[7];
    if (t < 200) scoreS[t] = ev / S;     // now holds attn
    __syncthreads();

    // ---- pooled from bf16 LDS rows: lane=e, wave w sums its 50 l's ----
    {
        const int comp = lane & 1;
        const int wk = lane >> 1;
        float acc = 0.f;
        #pragma unroll 5
        for (int l = w*50; l < w*50 + 50; l++) {
            const unsigned int word = hist2[l*HS + wk];
            const float hv = __uint_as_float(comp ? (word & 0xffff0000u) : (word << 16));
            acc = fmaf(scoreS[l], hv, acc);
        }
        part[w*64 + lane] = acc;
    }
    __syncthreads();

    if (t < 64) {
        const float c = cntw[0] + cntw[1] + cntw[2] + cntw[3];
        const float pooled = part[t] + part[64+t] + part[128+t] + part[192+t];
        PIN[(size_t)b*64 + t] = (part2[t] + part2[64+t] + part2[128+t] + part2[192+t]) / c;
        FUE[(size_t)b*64 + t] = user_emb[(size_t)user_id[b]*64 + t] + ufe[t] + pooled;
    }
}

// ---------------------------------------------------------------------------
// Kernel 2: total_prompt = relu(PIN (4096x64) @ Wp (64x3168) + bp)
// ---------------------------------------------------------------------------
__global__ __launch_bounds__(256) void k2_prompt_gemm(
    const float* __restrict__ PIN, const float* __restrict__ Wp,
    const float* __restrict__ bp, float* __restrict__ TP)
{
    __shared__ __align__(16) float As[64*65];
    __shared__ __align__(16) float Bs[64*128];
    const int t = threadIdx.x;
    const int m0 = blockIdx.y * 64;
    const int n0 = blockIdx.x * 128;
    {
        const int k = t & 63, ml = t >> 6;
        #pragma unroll
        for (int i = 0; i < 16; i++) {
            const int m = ml + i*4;
            As[m*65 + k] = PIN[(size_t)(m0+m)*64 + k];
        }
    }
    {
        const int n = t & 127, kl = t >> 7;
        const int gn = n0 + n;
        #pragma unroll
        for (int i = 0; i < 32; i++) {
            const int k = kl + i*2;
            Bs[k*128 + n] = (gn < NP) ? Wp[(size_t)k*NP + gn] : 0.f;
        }
    }
    __syncthreads();
    const int tx = t & 15, ty = t >> 4;
    float acc[4][8];
    #pragma unroll
    for (int i = 0; i < 4; i++)
        #pragma unroll
        for (int j = 0; j < 8; j++) acc[i][j] = 0.f;

    #pragma unroll 4
    for (int k = 0; k < 64; k++) {
        float a[4];
        #pragma unroll
        for (int i = 0; i < 4; i++) a[i] = As[(ty*4+i)*65 + k];
        const float4 b0 = *(const float4*)&Bs[k*128 + tx*8];
        const float4 b1 = *(const float4*)&Bs[k*128 + tx*8 + 4];
        #pragma unroll
        for (int i = 0; i < 4; i++) {
            acc[i][0] = fmaf(a[i], b0.x, acc[i][0]);
            acc[i][1] = fmaf(a[i], b0.y, acc[i][1]);
            acc[i][2] = fmaf(a[i], b0.z, acc[i][2]);
            acc[i][3] = fmaf(a[i], b0.w, acc[i][3]);
            acc[i][4] = fmaf(a[i], b1.x, acc[i][4]);
            acc[i][5] = fmaf(a[i], b1.y, acc[i][5]);
            acc[i][6] = fmaf(a[i], b1.z, acc[i][6]);
            acc[i][7] = fmaf(a[i], b1.w, acc[i][7]);
        }
    }
    #pragma unroll
    for (int i = 0; i < 4; i++) {
        const int m = m0 + ty*4 + i;
        #pragma unroll
        for (int j = 0; j < 8; j++) {
            const int n = n0 + tx*8 + j;
            if (n < NP) TP[(size_t)m*NP + n] = fmaxf(acc[i][j] + bp[n], 0.f);
        }
    }
}

// ---------------------------------------------------------------------------
// Kernel 3: prompt hypernetwork MLP.  grid=B, block=256, 1 item/thread.
// t<100: pos item t; 128<=t<228: neg item t-128.  pnet in LDS (12.5 KB),
// reduction via wave shuffles (no scratch) -> high occupancy.
// ---------------------------------------------------------------------------
__global__ __launch_bounds__(256, 4) void k3_prompt_mlp(
    const float* __restrict__ item_emb,
    const int* __restrict__ pos_fb, const int* __restrict__ pos_mask,
    const int* __restrict__ neg_fb, const int* __restrict__ neg_mask,
    const float* __restrict__ TP,
    float* __restrict__ POS_PE, float* __restrict__ out)
{
    const int b = blockIdx.x;
    const int t = threadIdx.x;
    const int w = t >> 6, lane = t & 63;
    __shared__ __align__(16) float pns[3136];   // w1|b1|w2|b2
    __shared__ float wsum[4][32];

    // stage pnet (784 float4), coalesced
    {
        const float4* pn4 = (const float4*)(TP + (size_t)b*NP + 32);
        float4* d4 = (float4*)pns;
        #pragma unroll
        for (int i = 0; i < 3; i++) d4[t + 256*i] = pn4[t + 256*i];
        if (t < 16) d4[768 + t] = pn4[768 + t];
    }

    bool act = false; int idx = 0;
    if (t < LFB) {
        act = pos_mask[(size_t)b*LFB + t] != 0;
        idx = pos_fb[(size_t)b*LFB + t];
    } else if (t >= 128 && t < 128 + LFB) {
        act = neg_mask[(size_t)b*LFB + (t-128)] != 0;
        idx = neg_fb[(size_t)b*LFB + (t-128)];
    }
    const float4* ur = (const float4*)(item_emb + (size_t)idx*64);
    __syncthreads();

    // layer 1: h[e] = relu(sum_k u[k]*w1[k][e] + b1[e]);  w1[k][e]=pns[k*32+e]
    float h[32];
    {
        const float4* b1v = (const float4*)&pns[2048];
        #pragma unroll
        for (int eb = 0; eb < 8; eb++) {
            const float4 bv = b1v[eb];
            h[eb*4+0] = bv.x; h[eb*4+1] = bv.y; h[eb*4+2] = bv.z; h[eb*4+3] = bv.w;
        }
    }
    #pragma unroll 4
    for (int kc = 0; kc < 16; kc++) {
        const float4 u4 = ur[kc];
        const float us[4] = {u4.x, u4.y, u4.z, u4.w};
        #pragma unroll
        for (int j = 0; j < 4; j++) {
            const float uk = us[j];
            const float4* wr = (const float4*)&pns[(kc*4 + j)*32];
            #pragma unroll
            for (int eb = 0; eb < 8; eb++) {
                const float4 wv = wr[eb];     // broadcast read
                h[eb*4+0] = fmaf(uk, wv.x, h[eb*4+0]);
                h[eb*4+1] = fmaf(uk, wv.y, h[eb*4+1]);
                h[eb*4+2] = fmaf(uk, wv.z, h[eb*4+2]);
                h[eb*4+3] = fmaf(uk, wv.w, h[eb*4+3]);
            }
        }
    }
    #pragma unroll
    for (int e = 0; e < 32; e++) h[e] = fmaxf(h[e], 0.f);

    // layer 2: o[p] = sum_e h[e]*w2[e][p] + b2[p];  w2[e][p]=pns[2080+e*32+p]
    float o[32];
    {
        const float4* b2v = (const float4*)&pns[3104];
        #pragma unroll
        for (int pb = 0; pb < 8; pb++) {
            const float4 bv = b2v[pb];
            o[pb*4+0] = bv.x; o[pb*4+1] = bv.y; o[pb*4+2] = bv.z; o[pb*4+3] = bv.w;
        }
    }
    #pragma unroll
    for (int e = 0; e < 32; e++) {
        const float he = h[e];
        const float4* wr = (const float4*)&pns[2080 + e*32];
        #pragma unroll
        for (int pb = 0; pb < 8; pb++) {
            const float4 wv = wr[pb];         // broadcast read
            o[pb*4+0] = fmaf(he, wv.x, o[pb*4+0]);
            o[pb*4+1] = fmaf(he, wv.y, o[pb*4+1]);
            o[pb*4+2] = fmaf(he, wv.z, o[pb*4+2]);
            o[pb*4+3] = fmaf(he, wv.w, o[pb*4+3]);
        }
    }

    // wave-level butterfly reduction of the 32-vector (masked)
    #pragma unroll
    for (int p = 0; p < 32; p++) {
        float v = act ? o[p] : 0.f;
        v += __shfl_xor(v, 1, 64);
        v += __shfl_xor(v, 2, 64);
        v += __shfl_xor(v, 4, 64);
        v += __shfl_xor(v, 8, 64);
        v += __shfl_xor(v, 16, 64);
        v += __shfl_xor(v, 32, 64);
        o[p] = v;                       // all lanes hold wave total
    }
    if (lane < 32) wsum[w][lane] = o[lane];
    __syncthreads();

    if (t < 32) {
        const float pp = wsum[0][t] + wsum[1][t];
        const float nn = wsum[2][t] + wsum[3][t];
        POS_PE[(size_t)b*32 + t] = pp;
        const float x = nn - pp;                   // -(pos - neg)
        out[BN + (size_t)b*32 + t] = fmaxf(x, 0.f) + log1pf(__expf(-fabsf(x)));
    }
}

// ---------------------------------------------------------------------------
// Kernel 4: fusion MLP + final dot.  8 batches per block. grid=512, block=256.
// ---------------------------------------------------------------------------
__global__ __launch_bounds__(256) void k4_fusion(
    const float* __restrict__ FUE, const float* __restrict__ FIE,
    const float* __restrict__ POS_PE, const float* __restrict__ TP,
    const float* __restrict__ Wf1, const float* __restrict__ bf1,
    const float* __restrict__ Wf2, const float* __restrict__ bf2,
    const float* __restrict__ Wf3, float* __restrict__ out)
{
    const int b0 = blockIdx.x * 8;
    const int t = threadIdx.x;
    __shared__ float fin[8*128];
    __shared__ float fuel[8*64];
    __shared__ float h1[8*200];
    __shared__ float h2[8*80];
    __shared__ float prod[8*64];

    #pragma unroll
    for (int i = 0; i < 4; i++) {
        const int idx = t + i*256;
        const int g = idx >> 7, k = idx & 127;
        float v;
        if (k < 64)      v = FIE[(size_t)(b0+g)*64 + k];
        else if (k < 96) v = POS_PE[(size_t)(b0+g)*32 + (k-64)];
        else             v = TP[(size_t)(b0+g)*NP + (k-96)];
        fin[idx] = v;
    }
    #pragma unroll
    for (int i = 0; i < 2; i++) {
        const int idx = t + i*256;
        fuel[idx] = FUE[(size_t)b0*64 + idx];
    }
    __syncthreads();

    for (int idx = t; idx < 8*200; idx += 256) {
        const int g = idx / 200, j = idx - g*200;
        float acc = bf1[j];
        const float* fg = fin + g*128;
        #pragma unroll 4
        for (int k = 0; k < 128; k++) acc = fmaf(fg[k], Wf1[k*200 + j], acc);
        h1[g*200 + j] = fmaxf(acc, 0.f);
    }
    __syncthreads();
    for (int idx = t; idx < 8*80; idx += 256) {
        const int g = idx / 80, j = idx - g*80;
        float acc = bf2[j];
        const float* hg = h1 + g*200;
        #pragma unroll 4
        for (int k = 0; k < 200; k++) acc = fmaf(hg[k], Wf2[k*80 + j], acc);
        h2[g*80 + j] = fmaxf(acc, 0.f);
    }
    __syncthreads();
    for (int idx = t; idx < 8*64; idx += 256) {
        const int g = idx >> 6;
        const int e = idx & 63;
        float acc = 0.f;
        const float* hg = h2 + g*80;
        #pragma unroll
        for (int k = 0; k < 80; k++) acc = fmaf(hg[k], Wf3[k*64 + e], acc);
        prod[idx] = acc * fuel[idx];
    }
    __syncthreads();
    if (t < 8) {
        float s = 0.f;
        const float* pg = prod + t*64;
        #pragma unroll
        for (int e = 0; e < 64; e++) s += pg[e];
        out[b0 + t] = s;
    }
}

// ---------------------------------------------------------------------------
extern "C" void kernel_launch(void* const* d_in, const int* in_sizes, int n_in,
                              void* d_out, int out_size, void* d_ws, size_t ws_size,
                              hipStream_t stream)
{
    const float* item_emb       = (const float*)d_in[0];
    const float* user_emb       = (const float*)d_in[1];
    const float* W_if           = (const float*)d_in[2];
    const float* b_if           = (const float*)d_in[3];
    const float* W_uf           = (const float*)d_in[4];
    const float* b_uf           = (const float*)d_in[5];
    const float* Wp             = (const float*)d_in[6];
    const float* bp             = (const float*)d_in[7];
    const float* Wf1            = (const float*)d_in[8];
    const float* bf1            = (const float*)d_in[9];
    const float* Wf2            = (const float*)d_in[10];
    const float* bf2            = (const float*)d_in[11];
    const float* Wf3            = (const float*)d_in[12];
    const float* item_features  = (const float*)d_in[13];
    const float* user_features  = (const float*)d_in[14];
    const int*   user_id        = (const int*)d_in[15];
    const int*   target_item_id = (const int*)d_in[16];
    const int*   history_item_id= (const int*)d_in[17];
    const int*   history_len    = (const int*)d_in[18];
    const int*   pos_fb         = (const int*)d_in[19];
    const int*   pos_mask       = (const int*)d_in[20];
    const int*   neg_fb         = (const int*)d_in[21];
    const int*   neg_mask       = (const int*)d_in[22];

    float* out = (float*)d_out;
    float* ws  = (float*)d_ws;
    float* FUE = ws + WS_FUE;
    float* FIE = ws + WS_FIE;
    float* PIN = ws + WS_PIN;
    float* TP  = ws + WS_TP;
    float* PPE = ws + WS_PPE;

    k1_gather_attn<<<dim3(BN), dim3(256), 0, stream>>>(
        item_emb, user_emb, W_if, b_if, W_uf, b_uf,
        item_features, user_features, user_id, target_item_id,
        history_item_id, history_len, pos_fb, pos_mask,
        FUE, FIE, PIN);

    k2_prompt_gemm<<<dim3(25, 64), dim3(256), 0, stream>>>(PIN, Wp, bp, TP);

    k3_prompt_mlp<<<dim3(BN), dim3(256), 0, stream>>>(
        item_emb, pos_fb, pos_mask, neg_fb, neg_mask, TP, PPE, out);

    k4_fusion<<<dim3(BN/8), dim3(256), 0, stream>>>(
        FUE, FIE, PPE, TP, Wf1, bf1, Wf2, bf2, Wf3, out);
}

// Round 4
// 389.254 us; speedup vs baseline: 1.2755x; 1.2755x over previous
//
#include <hip/hip_runtime.h>
#include <hip/hip_bf16.h>
#include <math.h>

#define BN 4096
#define LH 200
#define LFB 100
#define ED 64
#define PD 32
#define HD 32
#define NP 3168    // P + PNET = 32 + 3136
#define IV 100000

typedef unsigned int uint32;
typedef __attribute__((ext_vector_type(8))) short short8;
typedef __attribute__((ext_vector_type(4))) float f32x4;
union BF8 { uint32 u[4]; short8 v; };

__device__ __forceinline__ uint32 f2bf_pack(float x, float y) {
    uint32 ux = __float_as_uint(x);
    uint32 uy = __float_as_uint(y);
    uint32 bx = (ux + 0x7fffu + ((ux >> 16) & 1u)) >> 16;
    uint32 by = (uy + 0x7fffu + ((uy >> 16) & 1u)) >> 16;
    return (by << 16) | (bx & 0xffffu);
}

// ---------------------------------------------------------------------------
// Kernel 0: item_emb fp32 -> bf16 packed words (IEB, 32 words/row)
// ---------------------------------------------------------------------------
__global__ __launch_bounds__(256) void k0_cvt(
    const float* __restrict__ src, uint32* __restrict__ dst)
{
    const int i = blockIdx.x * 256 + threadIdx.x;   // < IV*32 = 3.2M exact
    const float2 v = ((const float2*)src)[i];
    dst[i] = f2bf_pack(v.x, v.y);
}

// ---------------------------------------------------------------------------
// Kernel 1: gathers + attention + pooling.  grid=B, block=256.
// All item_emb gathers go through bf16 IEB (128B rows -> half the lines).
// ---------------------------------------------------------------------------
#define HS 33
__global__ __launch_bounds__(256, 4) void k1_gather_attn(
    const uint32* __restrict__ IEB,
    const float* __restrict__ item_emb, const float* __restrict__ user_emb,
    const float* __restrict__ W_if, const float* __restrict__ b_if,
    const float* __restrict__ W_uf, const float* __restrict__ b_uf,
    const float* __restrict__ item_features, const float* __restrict__ user_features,
    const int* __restrict__ user_id, const int* __restrict__ target_item_id,
    const int* __restrict__ hist_id, const int* __restrict__ hist_len,
    const int* __restrict__ pos_fb, const int* __restrict__ pos_mask,
    float* __restrict__ FUE, float* __restrict__ FIE, float* __restrict__ PIN)
{
    const int b = blockIdx.x;
    const int t = threadIdx.x;
    const int w = t >> 6;
    const int lane = t & 63;

    __shared__ __align__(16) float tgt[64];
    __shared__ float feats[256];
    __shared__ float ufe[64];
    __shared__ float scoreS[256];
    __shared__ float wred[8];
    __shared__ float part[256];
    __shared__ float part2[256];
    __shared__ float cntw[4];
    __shared__ int   hids[200];
    __shared__ uint32 hist2[200*HS];   // bf16x2 packed rows

    if (t < 200) hids[t] = hist_id[(size_t)b*LH + t];
    feats[t] = (t < 128) ? item_features[(size_t)b*128 + t]
                         : user_features[(size_t)b*128 + (t-128)];
    if (t < 64) tgt[t] = item_emb[(size_t)target_item_id[b]*64 + t];
    __syncthreads();

    // ---- staging + in-flight scores: wave w owns rows [w*50, w*50+50) ----
    const int kk = lane & 31;          // word index within row
    const int hf = lane >> 5;          // which of the 2 rows this iter
    const float2 tf = ((const float2*)tgt)[kk];

    #pragma unroll 5
    for (int i = 0; i < 25; i++) {
        const int l = w*50 + i*2 + hf;
        const int id = hids[l];
        const uint32 word = IEB[(size_t)id*32 + kk];
        const float vx = __uint_as_float(word << 16);
        const float vy = __uint_as_float(word & 0xffff0000u);
        float sp = vx*tf.x + vy*tf.y;
        sp += __shfl_xor(sp, 1, 64);
        sp += __shfl_xor(sp, 2, 64);
        sp += __shfl_xor(sp, 4, 64);
        sp += __shfl_xor(sp, 8, 64);
        sp += __shfl_xor(sp, 16, 64);
        hist2[l*HS + kk] = word;
        if (kk == 0) scoreS[l] = sp * 0.125f;
    }

    // ---- pos-feedback masked mean (bf16 gather), 25 l's per wave ----
    {
        const int wk = lane >> 1;       // word in row
        const int comp = lane & 1;
        float acc = 0.f, cnt = 0.f;
        const int l0 = w * 25;
        const int* pid = pos_fb + (size_t)b*LFB;
        const int* pmk = pos_mask + (size_t)b*LFB;
        for (int g = 0; g < 5; g++) {
            const int base = l0 + g*5;
            int m0 = pmk[base+0], m1 = pmk[base+1], m2 = pmk[base+2],
                m3 = pmk[base+3], m4 = pmk[base+4];
            int i0 = pid[base+0], i1 = pid[base+1], i2 = pid[base+2],
                i3 = pid[base+3], i4 = pid[base+4];
            uint32 w0 = IEB[(size_t)i0*32 + wk];
            uint32 w1 = IEB[(size_t)i1*32 + wk];
            uint32 w2 = IEB[(size_t)i2*32 + wk];
            uint32 w3 = IEB[(size_t)i3*32 + wk];
            uint32 w4 = IEB[(size_t)i4*32 + wk];
            float v0 = __uint_as_float(comp ? (w0 & 0xffff0000u) : (w0 << 16));
            float v1 = __uint_as_float(comp ? (w1 & 0xffff0000u) : (w1 << 16));
            float v2 = __uint_as_float(comp ? (w2 & 0xffff0000u) : (w2 << 16));
            float v3 = __uint_as_float(comp ? (w3 & 0xffff0000u) : (w3 << 16));
            float v4 = __uint_as_float(comp ? (w4 & 0xffff0000u) : (w4 << 16));
            float f0 = m0 ? 1.f : 0.f, f1 = m1 ? 1.f : 0.f, f2 = m2 ? 1.f : 0.f,
                  f3 = m3 ? 1.f : 0.f, f4 = m4 ? 1.f : 0.f;
            acc = fmaf(f0, v0, acc); acc = fmaf(f1, v1, acc);
            acc = fmaf(f2, v2, acc); acc = fmaf(f3, v3, acc);
            acc = fmaf(f4, v4, acc);
            cnt += f0 + f1 + f2 + f3 + f4;
        }
        part2[w*64 + lane] = acc;
        if (lane == 0) cntw[w] = cnt;
    }

    // ---- feature embeddings (wave 0: item, wave 1: user) ----
    if (w == 0) {
        float acc = b_if[lane];
        #pragma unroll 4
        for (int k = 0; k < 128; k++) acc = fmaf(feats[k], W_if[k*64 + lane], acc);
        FIE[(size_t)b*64 + lane] = tgt[lane] + 1.f / (1.f + __expf(-acc));
    } else if (w == 1) {
        float acc = b_uf[lane];
        #pragma unroll 4
        for (int k = 0; k < 128; k++) acc = fmaf(feats[128 + k], W_uf[k*64 + lane], acc);
        ufe[lane] = 1.f / (1.f + __expf(-acc));
    }
    __syncthreads();

    // ---- softmax over 200 scores ----
    const int hl = hist_len[b];
    float sc = (t < 200 && t < hl) ? scoreS[t] : -1e9f;
    float m = sc;
    #pragma unroll
    for (int off = 32; off >= 1; off >>= 1) m = fmaxf(m, __shfl_xor(m, off, 64));
    if (lane == 0) wred[w] = m;
    __syncthreads();
    const float mx = fmaxf(fmaxf(wred[0], wred[1]), fmaxf(wred[2], wred[3]));
    const float ev = __expf(sc - mx);
    float s = ev;
    #pragma unroll
    for (int off = 32; off >= 1; off >>= 1) s += __shfl_xor(s, off, 64);
    if (lane == 0) wred[4 + w] = s;
    __syncthreads();
    const float S = wred[4] + wred[5] + wred[6] + wred[7];
    if (t < 200) scoreS[t] = ev / S;     // now holds attn
    __syncthreads();

    // ---- pooled from bf16 LDS rows ----
    {
        const int comp = lane & 1;
        const int wk = lane >> 1;
        float acc = 0.f;
        #pragma unroll 5
        for (int l = w*50; l < w*50 + 50; l++) {
            const uint32 word = hist2[l*HS + wk];
            const float hv = __uint_as_float(comp ? (word & 0xffff0000u) : (word << 16));
            acc = fmaf(scoreS[l], hv, acc);
        }
        part[w*64 + lane] = acc;
    }
    __syncthreads();

    if (t < 64) {
        const float c = cntw[0] + cntw[1] + cntw[2] + cntw[3];
        const float pooled = part[t] + part[64+t] + part[128+t] + part[192+t];
        PIN[(size_t)b*64 + t] = (part2[t] + part2[64+t] + part2[128+t] + part2[192+t]) / c;
        FUE[(size_t)b*64 + t] = user_emb[(size_t)user_id[b]*64 + t] + ufe[t] + pooled;
    }
}

// ---------------------------------------------------------------------------
// Kernel 2: total_prompt = relu(PIN @ Wp + bp); first 32 cols fp32 (TP32),
// remaining 3136 cols bf16-packed (TPN, 1568 words/row).
// ---------------------------------------------------------------------------
__global__ __launch_bounds__(256) void k2_prompt_gemm(
    const float* __restrict__ PIN, const float* __restrict__ Wp,
    const float* __restrict__ bp, float* __restrict__ TP32,
    uint32* __restrict__ TPN)
{
    __shared__ __align__(16) float As[64*65];
    __shared__ __align__(16) float Bs[64*128];
    const int t = threadIdx.x;
    const int m0 = blockIdx.y * 64;
    const int n0 = blockIdx.x * 128;
    {
        const int k = t & 63, ml = t >> 6;
        #pragma unroll
        for (int i = 0; i < 16; i++) {
            const int m = ml + i*4;
            As[m*65 + k] = PIN[(size_t)(m0+m)*64 + k];
        }
    }
    {
        const int n = t & 127, kl = t >> 7;
        const int gn = n0 + n;
        #pragma unroll
        for (int i = 0; i < 32; i++) {
            const int k = kl + i*2;
            Bs[k*128 + n] = (gn < NP) ? Wp[(size_t)k*NP + gn] : 0.f;
        }
    }
    __syncthreads();
    const int tx = t & 15, ty = t >> 4;
    float acc[4][8];
    #pragma unroll
    for (int i = 0; i < 4; i++)
        #pragma unroll
        for (int j = 0; j < 8; j++) acc[i][j] = 0.f;

    #pragma unroll 4
    for (int k = 0; k < 64; k++) {
        float a[4];
        #pragma unroll
        for (int i = 0; i < 4; i++) a[i] = As[(ty*4+i)*65 + k];
        const float4 b0 = *(const float4*)&Bs[k*128 + tx*8];
        const float4 b1 = *(const float4*)&Bs[k*128 + tx*8 + 4];
        #pragma unroll
        for (int i = 0; i < 4; i++) {
            acc[i][0] = fmaf(a[i], b0.x, acc[i][0]);
            acc[i][1] = fmaf(a[i], b0.y, acc[i][1]);
            acc[i][2] = fmaf(a[i], b0.z, acc[i][2]);
            acc[i][3] = fmaf(a[i], b0.w, acc[i][3]);
            acc[i][4] = fmaf(a[i], b1.x, acc[i][4]);
            acc[i][5] = fmaf(a[i], b1.y, acc[i][5]);
            acc[i][6] = fmaf(a[i], b1.z, acc[i][6]);
            acc[i][7] = fmaf(a[i], b1.w, acc[i][7]);
        }
    }
    #pragma unroll
    for (int i = 0; i < 4; i++) {
        const int m = m0 + ty*4 + i;
        #pragma unroll
        for (int jj = 0; jj < 4; jj++) {
            const int n = n0 + tx*8 + 2*jj;
            if (n < NP) {
                const float v0 = fmaxf(acc[i][2*jj]   + bp[n],   0.f);
                const float v1 = fmaxf(acc[i][2*jj+1] + bp[n+1], 0.f);
                if (n < 32) {
                    TP32[(size_t)m*32 + n]     = v0;
                    TP32[(size_t)m*32 + n + 1] = v1;
                } else {
                    TPN[(size_t)m*1568 + ((n-32) >> 1)] = f2bf_pack(v0, v1);
                }
            }
        }
    }
}

// ---------------------------------------------------------------------------
// Kernel 3: prompt hypernetwork via MFMA 16x16x32 bf16.  grid=B, block=256.
// Rows 0..99 = pos items, 100..199 = neg, 200..207 pad.  13 M-tiles of 16.
// A (items) gathered directly from IEB; w1/w2 repacked to B-fragment LDS.
// ---------------------------------------------------------------------------
__global__ __launch_bounds__(256) void k3_prompt_mlp(
    const uint32* __restrict__ IEB,
    const int* __restrict__ pos_fb, const int* __restrict__ pos_mask,
    const int* __restrict__ neg_fb, const int* __restrict__ neg_mask,
    const uint32* __restrict__ TPN,
    float* __restrict__ POS_PE, float* __restrict__ out)
{
    const int b = blockIdx.x, t = threadIdx.x;
    const int w = t >> 6, lane = t & 63;
    const int ml = lane & 15, q = lane >> 4;

    __shared__ uint32 w1b[32*36];     // [n][k-pair], pad 36
    __shared__ uint32 w2b[32*20];     // [n][k-pair], pad 20
    __shared__ float b1s[32], b2s[32];
    __shared__ float mP[208], mN[208];
    __shared__ int ids[208];
    __shared__ float Hs[4][16*36];    // per-wave H scratch fp32, pad 36
    __shared__ float wps[4][4][16];

    const uint32* pnw = TPN + (size_t)b*1568;
    // build w1b: w1[k][n] = pnet[k*32+n], k<64
    #pragma unroll
    for (int it = 0; it < 4; it++) {
        const int i = t + 256*it;            // 0..1023
        const int n = i >> 5, kw = i & 31;   // k = 2*kw
        const uint32 wa = pnw[kw*32 + (n >> 1)];
        const uint32 wb = pnw[kw*32 + 16 + (n >> 1)];
        const uint32 h0 = (n & 1) ? (wa >> 16) : (wa & 0xffffu);
        const uint32 h1 = (n & 1) ? (wb >> 16) : (wb & 0xffffu);
        w1b[n*36 + kw] = h0 | (h1 << 16);
    }
    // build w2b: w2[k][n] = pnet[2080 + k*32 + n], k<32 -> words 1040+
    #pragma unroll
    for (int it = 0; it < 2; it++) {
        const int i = t + 256*it;            // 0..511
        const int n = i >> 4, kw = i & 15;
        const uint32 wa = pnw[1040 + kw*32 + (n >> 1)];
        const uint32 wb = pnw[1040 + kw*32 + 16 + (n >> 1)];
        const uint32 h0 = (n & 1) ? (wa >> 16) : (wa & 0xffffu);
        const uint32 h1 = (n & 1) ? (wb >> 16) : (wb & 0xffffu);
        w2b[n*20 + kw] = h0 | (h1 << 16);
    }
    if (t < 16) {
        const uint32 wa = pnw[1024 + t];     // b1
        b1s[2*t]   = __uint_as_float(wa << 16);
        b1s[2*t+1] = __uint_as_float(wa & 0xffff0000u);
        const uint32 wb = pnw[1552 + t];     // b2
        b2s[2*t]   = __uint_as_float(wb << 16);
        b2s[2*t+1] = __uint_as_float(wb & 0xffff0000u);
    }
    if (t < 208) {
        int id = 0; float p = 0.f, nn = 0.f;
        if (t < 100) {
            id = pos_fb[(size_t)b*LFB + t];
            p  = (pos_mask[(size_t)b*LFB + t] != 0) ? 1.f : 0.f;
        } else if (t < 200) {
            const int li = t - 100;
            id = neg_fb[(size_t)b*LFB + li];
            nn = (neg_mask[(size_t)b*LFB + li] != 0) ? 1.f : 0.f;
        }
        ids[t] = id; mP[t] = p; mN[t] = nn;
    }
    __syncthreads();

    // hoist B fragments (same for all tiles)
    BF8 bf100, bf110, bf101, bf111, bf20, bf21;
    {
        uint4 u;
        u = *(const uint4*)&w1b[ml*36 + q*4];            bf100.u[0]=u.x; bf100.u[1]=u.y; bf100.u[2]=u.z; bf100.u[3]=u.w;
        u = *(const uint4*)&w1b[ml*36 + 16 + q*4];       bf110.u[0]=u.x; bf110.u[1]=u.y; bf110.u[2]=u.z; bf110.u[3]=u.w;
        u = *(const uint4*)&w1b[(16+ml)*36 + q*4];       bf101.u[0]=u.x; bf101.u[1]=u.y; bf101.u[2]=u.z; bf101.u[3]=u.w;
        u = *(const uint4*)&w1b[(16+ml)*36 + 16 + q*4];  bf111.u[0]=u.x; bf111.u[1]=u.y; bf111.u[2]=u.z; bf111.u[3]=u.w;
        u = *(const uint4*)&w2b[ml*20 + q*4];            bf20.u[0]=u.x;  bf20.u[1]=u.y;  bf20.u[2]=u.z;  bf20.u[3]=u.w;
        u = *(const uint4*)&w2b[(16+ml)*20 + q*4];       bf21.u[0]=u.x;  bf21.u[1]=u.y;  bf21.u[2]=u.z;  bf21.u[3]=u.w;
    }

    float accP0=0.f, accP1=0.f, accN0=0.f, accN1=0.f;
    float* hsw = Hs[w];

    for (int tile = w; tile < 13; tile += 4) {
        const int g = tile*16 + ml;
        const uint32* rowp = IEB + (size_t)ids[g]*32;
        BF8 a0, a1;
        { uint4 u = *(const uint4*)(rowp + q*4);      a0.u[0]=u.x; a0.u[1]=u.y; a0.u[2]=u.z; a0.u[3]=u.w; }
        { uint4 u = *(const uint4*)(rowp + 16 + q*4); a1.u[0]=u.x; a1.u[1]=u.y; a1.u[2]=u.z; a1.u[3]=u.w; }

        f32x4 c0 = {0.f,0.f,0.f,0.f}, c1 = {0.f,0.f,0.f,0.f};
        c0 = __builtin_amdgcn_mfma_f32_16x16x32_bf16(a0.v, bf100.v, c0, 0, 0, 0);
        c0 = __builtin_amdgcn_mfma_f32_16x16x32_bf16(a1.v, bf110.v, c0, 0, 0, 0);
        c1 = __builtin_amdgcn_mfma_f32_16x16x32_bf16(a0.v, bf101.v, c1, 0, 0, 0);
        c1 = __builtin_amdgcn_mfma_f32_16x16x32_bf16(a1.v, bf111.v, c1, 0, 0, 0);

        // relu + b1, C-layout (col=ml, row=q*4+r) -> Hs[row][col]
        #pragma unroll
        for (int r = 0; r < 4; r++) {
            const int row = q*4 + r;
            hsw[row*36 + ml]      = fmaxf(c0[r] + b1s[ml],      0.f);
            hsw[row*36 + 16 + ml] = fmaxf(c1[r] + b1s[16 + ml], 0.f);
        }
        asm volatile("s_waitcnt lgkmcnt(0)" ::: "memory");

        // A2-frag: H[m=ml][k=q*8+j]
        const float4 h0 = *(const float4*)&hsw[ml*36 + q*8];
        const float4 h1 = *(const float4*)&hsw[ml*36 + q*8 + 4];
        BF8 a2;
        a2.u[0] = f2bf_pack(h0.x, h0.y);
        a2.u[1] = f2bf_pack(h0.z, h0.w);
        a2.u[2] = f2bf_pack(h1.x, h1.y);
        a2.u[3] = f2bf_pack(h1.z, h1.w);

        f32x4 d0 = {0.f,0.f,0.f,0.f}, d1 = {0.f,0.f,0.f,0.f};
        d0 = __builtin_amdgcn_mfma_f32_16x16x32_bf16(a2.v, bf20.v, d0, 0, 0, 0);
        d1 = __builtin_amdgcn_mfma_f32_16x16x32_bf16(a2.v, bf21.v, d1, 0, 0, 0);

        #pragma unroll
        for (int r = 0; r < 4; r++) {
            const int g2 = tile*16 + q*4 + r;
            const float o0 = d0[r] + b2s[ml];
            const float o1 = d1[r] + b2s[16 + ml];
            accP0 = fmaf(mP[g2], o0, accP0);
            accP1 = fmaf(mP[g2], o1, accP1);
            accN0 = fmaf(mN[g2], o0, accN0);
            accN1 = fmaf(mN[g2], o1, accN1);
        }
    }

    // cross-quad reduce (cols live in lane&15, partial over quads)
    accP0 += __shfl_xor(accP0, 16, 64); accP0 += __shfl_xor(accP0, 32, 64);
    accP1 += __shfl_xor(accP1, 16, 64); accP1 += __shfl_xor(accP1, 32, 64);
    accN0 += __shfl_xor(accN0, 16, 64); accN0 += __shfl_xor(accN0, 32, 64);
    accN1 += __shfl_xor(accN1, 16, 64); accN1 += __shfl_xor(accN1, 32, 64);
    if (lane < 16) {
        wps[w][0][lane] = accP0;
        wps[w][1][lane] = accP1;
        wps[w][2][lane] = accN0;
        wps[w][3][lane] = accN1;
    }
    __syncthreads();

    if (t < 32) {
        const int nt = t >> 4, p = t & 15;
        const float pp = wps[0][nt][p] + wps[1][nt][p] + wps[2][nt][p] + wps[3][nt][p];
        const float nn = wps[0][2+nt][p] + wps[1][2+nt][p] + wps[2][2+nt][p] + wps[3][2+nt][p];
        POS_PE[(size_t)b*32 + t] = pp;
        const float x = nn - pp;                   // -(pos - neg)
        out[BN + (size_t)b*32 + t] = fmaxf(x, 0.f) + log1pf(__expf(-fabsf(x)));
    }
}

// ---------------------------------------------------------------------------
// Kernel 4: fusion MLP + final dot.  8 batches per block. grid=512, block=256.
// ---------------------------------------------------------------------------
__global__ __launch_bounds__(256) void k4_fusion(
    const float* __restrict__ FUE, const float* __restrict__ FIE,
    const float* __restrict__ POS_PE, const float* __restrict__ TP32,
    const float* __restrict__ Wf1, const float* __restrict__ bf1,
    const float* __restrict__ Wf2, const float* __restrict__ bf2,
    const float* __restrict__ Wf3, float* __restrict__ out)
{
    const int b0 = blockIdx.x * 8;
    const int t = threadIdx.x;
    __shared__ float fin[8*128];
    __shared__ float fuel[8*64];
    __shared__ float h1[8*200];
    __shared__ float h2[8*80];
    __shared__ float prod[8*64];

    #pragma unroll
    for (int i = 0; i < 4; i++) {
        const int idx = t + i*256;
        const int g = idx >> 7, k = idx & 127;
        float v;
        if (k < 64)      v = FIE[(size_t)(b0+g)*64 + k];
        else if (k < 96) v = POS_PE[(size_t)(b0+g)*32 + (k-64)];
        else             v = TP32[(size_t)(b0+g)*32 + (k-96)];
        fin[idx] = v;
    }
    #pragma unroll
    for (int i = 0; i < 2; i++) {
        const int idx = t + i*256;
        fuel[idx] = FUE[(size_t)b0*64 + idx];
    }
    __syncthreads();

    for (int idx = t; idx < 8*200; idx += 256) {
        const int g = idx / 200, j = idx - g*200;
        float acc = bf1[j];
        const float* fg = fin + g*128;
        #pragma unroll 4
        for (int k = 0; k < 128; k++) acc = fmaf(fg[k], Wf1[k*200 + j], acc);
        h1[g*200 + j] = fmaxf(acc, 0.f);
    }
    __syncthreads();
    for (int idx = t; idx < 8*80; idx += 256) {
        const int g = idx / 80, j = idx - g*80;
        float acc = bf2[j];
        const float* hg = h1 + g*200;
        #pragma unroll 4
        for (int k = 0; k < 200; k++) acc = fmaf(hg[k], Wf2[k*80 + j], acc);
        h2[g*80 + j] = fmaxf(acc, 0.f);
    }
    __syncthreads();
    for (int idx = t; idx < 8*64; idx += 256) {
        const int g = idx >> 6;
        const int e = idx & 63;
        float acc = 0.f;
        const float* hg = h2 + g*80;
        #pragma unroll
        for (int k = 0; k < 80; k++) acc = fmaf(hg[k], Wf3[k*64 + e], acc);
        prod[idx] = acc * fuel[idx];
    }
    __syncthreads();
    if (t < 8) {
        float s = 0.f;
        const float* pg = prod + t*64;
        #pragma unroll
        for (int e = 0; e < 64; e++) s += pg[e];
        out[b0 + t] = s;
    }
}

// ---------------------------------------------------------------------------
extern "C" void kernel_launch(void* const* d_in, const int* in_sizes, int n_in,
                              void* d_out, int out_size, void* d_ws, size_t ws_size,
                              hipStream_t stream)
{
    const float* item_emb       = (const float*)d_in[0];
    const float* user_emb       = (const float*)d_in[1];
    const float* W_if           = (const float*)d_in[2];
    const float* b_if           = (const float*)d_in[3];
    const float* W_uf           = (const float*)d_in[4];
    const float* b_uf           = (const float*)d_in[5];
    const float* Wp             = (const float*)d_in[6];
    const float* bp             = (const float*)d_in[7];
    const float* Wf1            = (const float*)d_in[8];
    const float* bf1            = (const float*)d_in[9];
    const float* Wf2            = (const float*)d_in[10];
    const float* bf2            = (const float*)d_in[11];
    const float* Wf3            = (const float*)d_in[12];
    const float* item_features  = (const float*)d_in[13];
    const float* user_features  = (const float*)d_in[14];
    const int*   user_id        = (const int*)d_in[15];
    const int*   target_item_id = (const int*)d_in[16];
    const int*   history_item_id= (const int*)d_in[17];
    const int*   history_len    = (const int*)d_in[18];
    const int*   pos_fb         = (const int*)d_in[19];
    const int*   pos_mask       = (const int*)d_in[20];
    const int*   neg_fb         = (const int*)d_in[21];
    const int*   neg_mask       = (const int*)d_in[22];

    float* out = (float*)d_out;
    float* ws  = (float*)d_ws;

    uint32* IEB  = (uint32*)ws;                 // IV*32 = 3.2M words
    float*  FUE  = ws + (size_t)IV*32;
    float*  FIE  = FUE + (size_t)BN*64;
    float*  PIN  = FIE + (size_t)BN*64;
    float*  TP32 = PIN + (size_t)BN*64;
    uint32* TPN  = (uint32*)(TP32 + (size_t)BN*32);
    float*  PPE  = (float*)(TPN + (size_t)BN*1568);

    k0_cvt<<<dim3(IV*32/256), dim3(256), 0, stream>>>(item_emb, IEB);

    k1_gather_attn<<<dim3(BN), dim3(256), 0, stream>>>(
        IEB, item_emb, user_emb, W_if, b_if, W_uf, b_uf,
        item_features, user_features, user_id, target_item_id,
        history_item_id, history_len, pos_fb, pos_mask,
        FUE, FIE, PIN);

    k2_prompt_gemm<<<dim3(25, 64), dim3(256), 0, stream>>>(PIN, Wp, bp, TP32, TPN);

    k3_prompt_mlp<<<dim3(BN), dim3(256), 0, stream>>>(
        IEB, pos_fb, pos_mask, neg_fb, neg_mask, TPN, PPE, out);

    k4_fusion<<<dim3(BN/8), dim3(256), 0, stream>>>(
        FUE, FIE, PPE, TP32, Wf1, bf1, Wf2, bf2, Wf3, out);
}

// Round 5
// 317.793 us; speedup vs baseline: 1.5623x; 1.2249x over previous
//
#include <hip/hip_runtime.h>
#include <hip/hip_bf16.h>
#include <math.h>

#define BN 4096
#define LH 200
#define LFB 100
#define ED 64
#define PD 32
#define HD 32
#define NP 3168    // P + PNET = 32 + 3136
#define IV 100000

typedef unsigned int uint32;
typedef __attribute__((ext_vector_type(8))) short short8;
typedef __attribute__((ext_vector_type(4))) float f32x4;
union BF8 { uint32 u[4]; short8 v; };

__device__ __forceinline__ uint32 f2bf_pack(float x, float y) {
    uint32 ux = __float_as_uint(x);
    uint32 uy = __float_as_uint(y);
    uint32 bx = (ux + 0x7fffu + ((ux >> 16) & 1u)) >> 16;
    uint32 by = (uy + 0x7fffu + ((uy >> 16) & 1u)) >> 16;
    return (by << 16) | (bx & 0xffffu);
}

// ---------------------------------------------------------------------------
// Kernel 0: item_emb fp32 -> bf16 packed words (IEB, 32 words/row)
// ---------------------------------------------------------------------------
__global__ __launch_bounds__(256) void k0_cvt(
    const float* __restrict__ src, uint32* __restrict__ dst)
{
    const int i = blockIdx.x * 256 + threadIdx.x;   // < IV*32 = 3.2M exact
    const float2 v = ((const float2*)src)[i];
    dst[i] = f2bf_pack(v.x, v.y);
}

// ---------------------------------------------------------------------------
// Kernel 0b: Wp (64 x NP fp32) -> WpB bf16 packed, layout [n][kw] kw=k-pair
// grid (13, 32) block 256
// ---------------------------------------------------------------------------
__global__ __launch_bounds__(256) void k0b_cvt_wp(
    const float* __restrict__ Wp, uint32* __restrict__ WpB)
{
    const int n = blockIdx.x * 256 + threadIdx.x;
    const int kw = blockIdx.y;
    if (n < NP) {
        const float a = Wp[(size_t)(2*kw)*NP + n];
        const float b = Wp[(size_t)(2*kw+1)*NP + n];
        WpB[(size_t)n*32 + kw] = f2bf_pack(a, b);
    }
}

// ---------------------------------------------------------------------------
// Kernel 1: gathers + attention + pooling.  grid=B, block=256.
// Decoupled: pure staging (pipelined gathers), then per-thread scores from
// LDS (conflict-free), shuffle softmax, LDS pooling.
// ---------------------------------------------------------------------------
#define HS 33
__global__ __launch_bounds__(256, 4) void k1_gather_attn(
    const uint32* __restrict__ IEB,
    const float* __restrict__ item_emb, const float* __restrict__ user_emb,
    const float* __restrict__ W_if, const float* __restrict__ b_if,
    const float* __restrict__ W_uf, const float* __restrict__ b_uf,
    const float* __restrict__ item_features, const float* __restrict__ user_features,
    const int* __restrict__ user_id, const int* __restrict__ target_item_id,
    const int* __restrict__ hist_id, const int* __restrict__ hist_len,
    const int* __restrict__ pos_fb, const int* __restrict__ pos_mask,
    float* __restrict__ FUE, float* __restrict__ FIE, uint32* __restrict__ PINB)
{
    const int b = blockIdx.x;
    const int t = threadIdx.x;
    const int w = t >> 6;
    const int lane = t & 63;

    __shared__ __align__(16) float tgt[64];
    __shared__ float feats[256];
    __shared__ float ufe[64];
    __shared__ float scoreS[256];
    __shared__ float wred[8];
    __shared__ float part[256];
    __shared__ float part2[256];
    __shared__ float cntw[4];
    __shared__ int   hids[200];
    __shared__ uint32 hist2[200*HS];   // bf16x2 packed rows

    const int hl = hist_len[b];
    if (t < 200) hids[t] = hist_id[(size_t)b*LH + t];
    feats[t] = (t < 128) ? item_features[(size_t)b*128 + t]
                         : user_features[(size_t)b*128 + (t-128)];
    if (t < 64) tgt[t] = item_emb[(size_t)target_item_id[b]*64 + t];
    __syncthreads();

    // ---- Phase A: pure staging, wave w owns rows [w*50, w*50+50) ----
    const int kk = lane & 31;          // word index within row
    const int hf = lane >> 5;          // which of the 2 rows this iter
    #pragma unroll
    for (int i = 0; i < 25; i++) {
        const int l = w*50 + i*2 + hf;
        hist2[l*HS + kk] = IEB[(size_t)hids[l]*32 + kk];
    }

    // ---- pos-feedback masked mean (bf16 gather), 25 l's per wave ----
    {
        const int wk = lane >> 1;       // word in row
        const int comp = lane & 1;
        float acc = 0.f, cnt = 0.f;
        const int l0 = w * 25;
        const int* pid = pos_fb + (size_t)b*LFB;
        const int* pmk = pos_mask + (size_t)b*LFB;
        for (int g = 0; g < 5; g++) {
            const int base = l0 + g*5;
            int m0 = pmk[base+0], m1 = pmk[base+1], m2 = pmk[base+2],
                m3 = pmk[base+3], m4 = pmk[base+4];
            int i0 = pid[base+0], i1 = pid[base+1], i2 = pid[base+2],
                i3 = pid[base+3], i4 = pid[base+4];
            uint32 w0 = IEB[(size_t)i0*32 + wk];
            uint32 w1 = IEB[(size_t)i1*32 + wk];
            uint32 w2 = IEB[(size_t)i2*32 + wk];
            uint32 w3 = IEB[(size_t)i3*32 + wk];
            uint32 w4 = IEB[(size_t)i4*32 + wk];
            float v0 = __uint_as_float(comp ? (w0 & 0xffff0000u) : (w0 << 16));
            float v1 = __uint_as_float(comp ? (w1 & 0xffff0000u) : (w1 << 16));
            float v2 = __uint_as_float(comp ? (w2 & 0xffff0000u) : (w2 << 16));
            float v3 = __uint_as_float(comp ? (w3 & 0xffff0000u) : (w3 << 16));
            float v4 = __uint_as_float(comp ? (w4 & 0xffff0000u) : (w4 << 16));
            float f0 = m0 ? 1.f : 0.f, f1 = m1 ? 1.f : 0.f, f2 = m2 ? 1.f : 0.f,
                  f3 = m3 ? 1.f : 0.f, f4 = m4 ? 1.f : 0.f;
            acc = fmaf(f0, v0, acc); acc = fmaf(f1, v1, acc);
            acc = fmaf(f2, v2, acc); acc = fmaf(f3, v3, acc);
            acc = fmaf(f4, v4, acc);
            cnt += f0 + f1 + f2 + f3 + f4;
        }
        part2[w*64 + lane] = acc;
        if (lane == 0) cntw[w] = cnt;
    }

    // ---- feature embeddings (wave 0: item, wave 1: user) ----
    if (w == 0) {
        float acc = b_if[lane];
        #pragma unroll 4
        for (int k = 0; k < 128; k++) acc = fmaf(feats[k], W_if[k*64 + lane], acc);
        FIE[(size_t)b*64 + lane] = tgt[lane] + 1.f / (1.f + __expf(-acc));
    } else if (w == 1) {
        float acc = b_uf[lane];
        #pragma unroll 4
        for (int k = 0; k < 128; k++) acc = fmaf(feats[128 + k], W_uf[k*64 + lane], acc);
        ufe[lane] = 1.f / (1.f + __expf(-acc));
    }
    __syncthreads();

    // ---- Phase B: per-thread score from LDS row (conflict-free) ----
    float sc = -1e9f;
    if (t < 200) {
        const uint32* hrow = &hist2[t*HS];
        float acc = 0.f;
        #pragma unroll 8
        for (int k2 = 0; k2 < 32; k2++) {
            const uint32 word = hrow[k2];
            const float2 tf = ((const float2*)tgt)[k2];   // broadcast
            acc = fmaf(__uint_as_float(word << 16),        tf.x, acc);
            acc = fmaf(__uint_as_float(word & 0xffff0000u), tf.y, acc);
        }
        if (t < hl) sc = acc * 0.125f;
    }

    // ---- softmax over 200 scores ----
    float m = sc;
    #pragma unroll
    for (int off = 32; off >= 1; off >>= 1) m = fmaxf(m, __shfl_xor(m, off, 64));
    if (lane == 0) wred[w] = m;
    __syncthreads();
    const float mx = fmaxf(fmaxf(wred[0], wred[1]), fmaxf(wred[2], wred[3]));
    const float ev = __expf(sc - mx);
    float s = ev;
    #pragma unroll
    for (int off = 32; off >= 1; off >>= 1) s += __shfl_xor(s, off, 64);
    if (lane == 0) wred[4 + w] = s;
    __syncthreads();
    const float S = wred[4] + wred[5] + wred[6] + wred[7];
    if (t < 200) scoreS[t] = ev / S;     // attn
    __syncthreads();

    // ---- pooled from bf16 LDS rows ----
    {
        const int comp = lane & 1;
        const int wk = lane >> 1;
        float acc = 0.f;
        #pragma unroll 5
        for (int l = w*50; l < w*50 + 50; l++) {
            const uint32 word = hist2[l*HS + wk];
            const float hv = __uint_as_float(comp ? (word & 0xffff0000u) : (word << 16));
            acc = fmaf(scoreS[l], hv, acc);
        }
        part[w*64 + lane] = acc;
    }
    __syncthreads();

    if (t < 64) {
        const float c = cntw[0] + cntw[1] + cntw[2] + cntw[3];
        const float pooled = part[t] + part[64+t] + part[128+t] + part[192+t];
        const float pinv = (part2[t] + part2[64+t] + part2[128+t] + part2[192+t]) / c;
        FUE[(size_t)b*64 + t] = user_emb[(size_t)user_id[b]*64 + t] + ufe[t] + pooled;
        const float po = __shfl_xor(pinv, 1, 64);
        if ((t & 1) == 0) PINB[(size_t)b*32 + (t >> 1)] = f2bf_pack(pinv, po);
    }
}

// ---------------------------------------------------------------------------
// Kernel 2: total_prompt = relu(PIN @ Wp + bp) via MFMA bf16.
// Block tile 64(m) x 128(n), K=64.  grid=(25,64), block=256.
// Output: first 32 cols fp32 (TP32), rest bf16-packed (TPN).
// ---------------------------------------------------------------------------
__global__ __launch_bounds__(256) void k2_prompt_gemm(
    const uint32* __restrict__ PINB, const uint32* __restrict__ WpB,
    const float* __restrict__ bp, float* __restrict__ TP32,
    uint32* __restrict__ TPN)
{
    __shared__ uint32 As[64*36];    // [m][kw] pad 36
    __shared__ uint32 Bs[128*36];   // [n][kw] pad 36
    __shared__ float bps[128];
    const int t = threadIdx.x;
    const int m0 = blockIdx.y * 64;
    const int n0 = blockIdx.x * 128;

    {   // stage A tile: 64 rows x 32 words
        const int m = t >> 2, kw0 = (t & 3) * 8;
        const uint4 u0 = *(const uint4*)&PINB[(size_t)(m0+m)*32 + kw0];
        const uint4 u1 = *(const uint4*)&PINB[(size_t)(m0+m)*32 + kw0 + 4];
        *(uint4*)&As[m*36 + kw0]     = u0;
        *(uint4*)&As[m*36 + kw0 + 4] = u1;
    }
    {   // stage B tile: 128 rows x 32 words
        const int n = t >> 1, kw0 = (t & 1) * 16;
        const int gn = n0 + n;
        if (gn < NP) {
            #pragma unroll
            for (int j = 0; j < 4; j++) {
                const uint4 u = *(const uint4*)&WpB[(size_t)gn*32 + kw0 + 4*j];
                *(uint4*)&Bs[n*36 + kw0 + 4*j] = u;
            }
        } else {
            #pragma unroll
            for (int j = 0; j < 16; j++) Bs[n*36 + kw0 + j] = 0u;
        }
    }
    if (t < 128) bps[t] = (n0 + t < NP) ? bp[n0 + t] : 0.f;
    __syncthreads();

    const int w = t >> 6, lane = t & 63, ml = lane & 15, q = lane >> 4;

    BF8 a0, a1;
    { uint4 u = *(const uint4*)&As[(w*16+ml)*36 + q*4];      a0.u[0]=u.x; a0.u[1]=u.y; a0.u[2]=u.z; a0.u[3]=u.w; }
    { uint4 u = *(const uint4*)&As[(w*16+ml)*36 + 16 + q*4]; a1.u[0]=u.x; a1.u[1]=u.y; a1.u[2]=u.z; a1.u[3]=u.w; }

    f32x4 c[8];
    #pragma unroll
    for (int nb = 0; nb < 8; nb++) {
        BF8 b0, b1;
        { uint4 u = *(const uint4*)&Bs[(nb*16+ml)*36 + q*4];      b0.u[0]=u.x; b0.u[1]=u.y; b0.u[2]=u.z; b0.u[3]=u.w; }
        { uint4 u = *(const uint4*)&Bs[(nb*16+ml)*36 + 16 + q*4]; b1.u[0]=u.x; b1.u[1]=u.y; b1.u[2]=u.z; b1.u[3]=u.w; }
        f32x4 cc = {0.f, 0.f, 0.f, 0.f};
        cc = __builtin_amdgcn_mfma_f32_16x16x32_bf16(a0.v, b0.v, cc, 0, 0, 0);
        cc = __builtin_amdgcn_mfma_f32_16x16x32_bf16(a1.v, b1.v, cc, 0, 0, 0);
        c[nb] = cc;
    }

    // epilogue: C row = m0+w*16+q*4+r, col = n0+nb*16+ml
    #pragma unroll
    for (int nb = 0; nb < 8; nb++) {
        const int n = n0 + nb*16 + ml;
        const float bv = bps[nb*16 + ml];
        #pragma unroll
        for (int r = 0; r < 4; r++) {
            const int m = m0 + w*16 + q*4 + r;
            const float v = fmaxf(c[nb][r] + bv, 0.f);
            const float vp = __shfl_xor(v, 1, 64);
            if (n < 32) {
                TP32[(size_t)m*32 + n] = v;
            } else if (n < NP && (ml & 1) == 0) {
                TPN[(size_t)m*1568 + ((n - 32) >> 1)] = f2bf_pack(v, vp);
            }
        }
    }
}

// ---------------------------------------------------------------------------
// Kernel 3: prompt hypernetwork via MFMA 16x16x32 bf16.  grid=B, block=256.
// ---------------------------------------------------------------------------
__global__ __launch_bounds__(256) void k3_prompt_mlp(
    const uint32* __restrict__ IEB,
    const int* __restrict__ pos_fb, const int* __restrict__ pos_mask,
    const int* __restrict__ neg_fb, const int* __restrict__ neg_mask,
    const uint32* __restrict__ TPN,
    float* __restrict__ POS_PE, float* __restrict__ out)
{
    const int b = blockIdx.x, t = threadIdx.x;
    const int w = t >> 6, lane = t & 63;
    const int ml = lane & 15, q = lane >> 4;

    __shared__ uint32 w1b[32*36];
    __shared__ uint32 w2b[32*20];
    __shared__ float b1s[32], b2s[32];
    __shared__ float mP[208], mN[208];
    __shared__ int ids[208];
    __shared__ float Hs[4][16*36];
    __shared__ float wps[4][4][16];

    const uint32* pnw = TPN + (size_t)b*1568;
    #pragma unroll
    for (int it = 0; it < 4; it++) {
        const int i = t + 256*it;
        const int n = i >> 5, kw = i & 31;
        const uint32 wa = pnw[kw*32 + (n >> 1)];
        const uint32 wb = pnw[kw*32 + 16 + (n >> 1)];
        const uint32 h0 = (n & 1) ? (wa >> 16) : (wa & 0xffffu);
        const uint32 h1 = (n & 1) ? (wb >> 16) : (wb & 0xffffu);
        w1b[n*36 + kw] = h0 | (h1 << 16);
    }
    #pragma unroll
    for (int it = 0; it < 2; it++) {
        const int i = t + 256*it;
        const int n = i >> 4, kw = i & 15;
        const uint32 wa = pnw[1040 + kw*32 + (n >> 1)];
        const uint32 wb = pnw[1040 + kw*32 + 16 + (n >> 1)];
        const uint32 h0 = (n & 1) ? (wa >> 16) : (wa & 0xffffu);
        const uint32 h1 = (n & 1) ? (wb >> 16) : (wb & 0xffffu);
        w2b[n*20 + kw] = h0 | (h1 << 16);
    }
    if (t < 16) {
        const uint32 wa = pnw[1024 + t];
        b1s[2*t]   = __uint_as_float(wa << 16);
        b1s[2*t+1] = __uint_as_float(wa & 0xffff0000u);
        const uint32 wb = pnw[1552 + t];
        b2s[2*t]   = __uint_as_float(wb << 16);
        b2s[2*t+1] = __uint_as_float(wb & 0xffff0000u);
    }
    if (t < 208) {
        int id = 0; float p = 0.f, nn = 0.f;
        if (t < 100) {
            id = pos_fb[(size_t)b*LFB + t];
            p  = (pos_mask[(size_t)b*LFB + t] != 0) ? 1.f : 0.f;
        } else if (t < 200) {
            const int li = t - 100;
            id = neg_fb[(size_t)b*LFB + li];
            nn = (neg_mask[(size_t)b*LFB + li] != 0) ? 1.f : 0.f;
        }
        ids[t] = id; mP[t] = p; mN[t] = nn;
    }
    __syncthreads();

    BF8 bf100, bf110, bf101, bf111, bf20, bf21;
    {
        uint4 u;
        u = *(const uint4*)&w1b[ml*36 + q*4];            bf100.u[0]=u.x; bf100.u[1]=u.y; bf100.u[2]=u.z; bf100.u[3]=u.w;
        u = *(const uint4*)&w1b[ml*36 + 16 + q*4];       bf110.u[0]=u.x; bf110.u[1]=u.y; bf110.u[2]=u.z; bf110.u[3]=u.w;
        u = *(const uint4*)&w1b[(16+ml)*36 + q*4];       bf101.u[0]=u.x; bf101.u[1]=u.y; bf101.u[2]=u.z; bf101.u[3]=u.w;
        u = *(const uint4*)&w1b[(16+ml)*36 + 16 + q*4];  bf111.u[0]=u.x; bf111.u[1]=u.y; bf111.u[2]=u.z; bf111.u[3]=u.w;
        u = *(const uint4*)&w2b[ml*20 + q*4];            bf20.u[0]=u.x;  bf20.u[1]=u.y;  bf20.u[2]=u.z;  bf20.u[3]=u.w;
        u = *(const uint4*)&w2b[(16+ml)*20 + q*4];       bf21.u[0]=u.x;  bf21.u[1]=u.y;  bf21.u[2]=u.z;  bf21.u[3]=u.w;
    }

    float accP0=0.f, accP1=0.f, accN0=0.f, accN1=0.f;
    float* hsw = Hs[w];

    for (int tile = w; tile < 13; tile += 4) {
        const int g = tile*16 + ml;
        const uint32* rowp = IEB + (size_t)ids[g]*32;
        BF8 a0, a1;
        { uint4 u = *(const uint4*)(rowp + q*4);      a0.u[0]=u.x; a0.u[1]=u.y; a0.u[2]=u.z; a0.u[3]=u.w; }
        { uint4 u = *(const uint4*)(rowp + 16 + q*4); a1.u[0]=u.x; a1.u[1]=u.y; a1.u[2]=u.z; a1.u[3]=u.w; }

        f32x4 c0 = {0.f,0.f,0.f,0.f}, c1 = {0.f,0.f,0.f,0.f};
        c0 = __builtin_amdgcn_mfma_f32_16x16x32_bf16(a0.v, bf100.v, c0, 0, 0, 0);
        c0 = __builtin_amdgcn_mfma_f32_16x16x32_bf16(a1.v, bf110.v, c0, 0, 0, 0);
        c1 = __builtin_amdgcn_mfma_f32_16x16x32_bf16(a0.v, bf101.v, c1, 0, 0, 0);
        c1 = __builtin_amdgcn_mfma_f32_16x16x32_bf16(a1.v, bf111.v, c1, 0, 0, 0);

        #pragma unroll
        for (int r = 0; r < 4; r++) {
            const int row = q*4 + r;
            hsw[row*36 + ml]      = fmaxf(c0[r] + b1s[ml],      0.f);
            hsw[row*36 + 16 + ml] = fmaxf(c1[r] + b1s[16 + ml], 0.f);
        }
        asm volatile("s_waitcnt lgkmcnt(0)" ::: "memory");

        const float4 h0 = *(const float4*)&hsw[ml*36 + q*8];
        const float4 h1 = *(const float4*)&hsw[ml*36 + q*8 + 4];
        BF8 a2;
        a2.u[0] = f2bf_pack(h0.x, h0.y);
        a2.u[1] = f2bf_pack(h0.z, h0.w);
        a2.u[2] = f2bf_pack(h1.x, h1.y);
        a2.u[3] = f2bf_pack(h1.z, h1.w);

        f32x4 d0 = {0.f,0.f,0.f,0.f}, d1 = {0.f,0.f,0.f,0.f};
        d0 = __builtin_amdgcn_mfma_f32_16x16x32_bf16(a2.v, bf20.v, d0, 0, 0, 0);
        d1 = __builtin_amdgcn_mfma_f32_16x16x32_bf16(a2.v, bf21.v, d1, 0, 0, 0);

        #pragma unroll
        for (int r = 0; r < 4; r++) {
            const int g2 = tile*16 + q*4 + r;
            const float o0 = d0[r] + b2s[ml];
            const float o1 = d1[r] + b2s[16 + ml];
            accP0 = fmaf(mP[g2], o0, accP0);
            accP1 = fmaf(mP[g2], o1, accP1);
            accN0 = fmaf(mN[g2], o0, accN0);
            accN1 = fmaf(mN[g2], o1, accN1);
        }
    }

    accP0 += __shfl_xor(accP0, 16, 64); accP0 += __shfl_xor(accP0, 32, 64);
    accP1 += __shfl_xor(accP1, 16, 64); accP1 += __shfl_xor(accP1, 32, 64);
    accN0 += __shfl_xor(accN0, 16, 64); accN0 += __shfl_xor(accN0, 32, 64);
    accN1 += __shfl_xor(accN1, 16, 64); accN1 += __shfl_xor(accN1, 32, 64);
    if (lane < 16) {
        wps[w][0][lane] = accP0;
        wps[w][1][lane] = accP1;
        wps[w][2][lane] = accN0;
        wps[w][3][lane] = accN1;
    }
    __syncthreads();

    if (t < 32) {
        const int nt = t >> 4, p = t & 15;
        const float pp = wps[0][nt][p] + wps[1][nt][p] + wps[2][nt][p] + wps[3][nt][p];
        const float nn = wps[0][2+nt][p] + wps[1][2+nt][p] + wps[2][2+nt][p] + wps[3][2+nt][p];
        POS_PE[(size_t)b*32 + t] = pp;
        const float x = nn - pp;
        out[BN + (size_t)b*32 + t] = fmaxf(x, 0.f) + log1pf(__expf(-fabsf(x)));
    }
}

// ---------------------------------------------------------------------------
// Kernel 4: fusion MLP + final dot.  8 batches per block. grid=512, block=256.
// ---------------------------------------------------------------------------
__global__ __launch_bounds__(256) void k4_fusion(
    const float* __restrict__ FUE, const float* __restrict__ FIE,
    const float* __restrict__ POS_PE, const float* __restrict__ TP32,
    const float* __restrict__ Wf1, const float* __restrict__ bf1,
    const float* __restrict__ Wf2, const float* __restrict__ bf2,
    const float* __restrict__ Wf3, float* __restrict__ out)
{
    const int b0 = blockIdx.x * 8;
    const int t = threadIdx.x;
    __shared__ float fin[8*128];
    __shared__ float fuel[8*64];
    __shared__ float h1[8*200];
    __shared__ float h2[8*80];
    __shared__ float prod[8*64];

    #pragma unroll
    for (int i = 0; i < 4; i++) {
        const int idx = t + i*256;
        const int g = idx >> 7, k = idx & 127;
        float v;
        if (k < 64)      v = FIE[(size_t)(b0+g)*64 + k];
        else if (k < 96) v = POS_PE[(size_t)(b0+g)*32 + (k-64)];
        else             v = TP32[(size_t)(b0+g)*32 + (k-96)];
        fin[idx] = v;
    }
    #pragma unroll
    for (int i = 0; i < 2; i++) {
        const int idx = t + i*256;
        fuel[idx] = FUE[(size_t)b0*64 + idx];
    }
    __syncthreads();

    for (int idx = t; idx < 8*200; idx += 256) {
        const int g = idx / 200, j = idx - g*200;
        float acc = bf1[j];
        const float* fg = fin + g*128;
        #pragma unroll 4
        for (int k = 0; k < 128; k++) acc = fmaf(fg[k], Wf1[k*200 + j], acc);
        h1[g*200 + j] = fmaxf(acc, 0.f);
    }
    __syncthreads();
    for (int idx = t; idx < 8*80; idx += 256) {
        const int g = idx / 80, j = idx - g*80;
        float acc = bf2[j];
        const float* hg = h1 + g*200;
        #pragma unroll 4
        for (int k = 0; k < 200; k++) acc = fmaf(hg[k], Wf2[k*80 + j], acc);
        h2[g*80 + j] = fmaxf(acc, 0.f);
    }
    __syncthreads();
    for (int idx = t; idx < 8*64; idx += 256) {
        const int g = idx >> 6;
        const int e = idx & 63;
        float acc = 0.f;
        const float* hg = h2 + g*80;
        #pragma unroll
        for (int k = 0; k < 80; k++) acc = fmaf(hg[k], Wf3[k*64 + e], acc);
        prod[idx] = acc * fuel[idx];
    }
    __syncthreads();
    if (t < 8) {
        float s = 0.f;
        const float* pg = prod + t*64;
        #pragma unroll
        for (int e = 0; e < 64; e++) s += pg[e];
        out[b0 + t] = s;
    }
}

// ---------------------------------------------------------------------------
extern "C" void kernel_launch(void* const* d_in, const int* in_sizes, int n_in,
                              void* d_out, int out_size, void* d_ws, size_t ws_size,
                              hipStream_t stream)
{
    const float* item_emb       = (const float*)d_in[0];
    const float* user_emb       = (const float*)d_in[1];
    const float* W_if           = (const float*)d_in[2];
    const float* b_if           = (const float*)d_in[3];
    const float* W_uf           = (const float*)d_in[4];
    const float* b_uf           = (const float*)d_in[5];
    const float* Wp             = (const float*)d_in[6];
    const float* bp             = (const float*)d_in[7];
    const float* Wf1            = (const float*)d_in[8];
    const float* bf1            = (const float*)d_in[9];
    const float* Wf2            = (const float*)d_in[10];
    const float* bf2            = (const float*)d_in[11];
    const float* Wf3            = (const float*)d_in[12];
    const float* item_features  = (const float*)d_in[13];
    const float* user_features  = (const float*)d_in[14];
    const int*   user_id        = (const int*)d_in[15];
    const int*   target_item_id = (const int*)d_in[16];
    const int*   history_item_id= (const int*)d_in[17];
    const int*   history_len    = (const int*)d_in[18];
    const int*   pos_fb         = (const int*)d_in[19];
    const int*   pos_mask       = (const int*)d_in[20];
    const int*   neg_fb         = (const int*)d_in[21];
    const int*   neg_mask       = (const int*)d_in[22];

    float* out = (float*)d_out;
    float* ws  = (float*)d_ws;

    uint32* IEB  = (uint32*)ws;                       // IV*32
    uint32* WpB  = IEB + (size_t)IV*32;               // NP*32 = 101376
    uint32* PINB = WpB + (size_t)NP*32;               // BN*32
    float*  FUE  = (float*)(PINB + (size_t)BN*32);
    float*  FIE  = FUE + (size_t)BN*64;
    float*  TP32 = FIE + (size_t)BN*64;               // BN*32
    uint32* TPN  = (uint32*)(TP32 + (size_t)BN*32);   // BN*1568
    float*  PPE  = (float*)(TPN + (size_t)BN*1568);

    k0_cvt<<<dim3(IV*32/256), dim3(256), 0, stream>>>(item_emb, IEB);
    k0b_cvt_wp<<<dim3(13, 32), dim3(256), 0, stream>>>(Wp, WpB);

    k1_gather_attn<<<dim3(BN), dim3(256), 0, stream>>>(
        IEB, item_emb, user_emb, W_if, b_if, W_uf, b_uf,
        item_features, user_features, user_id, target_item_id,
        history_item_id, history_len, pos_fb, pos_mask,
        FUE, FIE, PINB);

    k2_prompt_gemm<<<dim3(25, 64), dim3(256), 0, stream>>>(PINB, WpB, bp, TP32, TPN);

    k3_prompt_mlp<<<dim3(BN), dim3(256), 0, stream>>>(
        IEB, pos_fb, pos_mask, neg_fb, neg_mask, TPN, PPE, out);

    k4_fusion<<<dim3(BN/8), dim3(256), 0, stream>>>(
        FUE, FIE, PPE, TP32, Wf1, bf1, Wf2, bf2, Wf3, out);
}

// Round 6
// 264.541 us; speedup vs baseline: 1.8768x; 1.2013x over previous
//
#include <hip/hip_runtime.h>
#include <hip/hip_bf16.h>
#include <hip/hip_fp16.h>
#include <math.h>

#define BN 4096
#define LH 200
#define LFB 100
#define ED 64
#define PD 32
#define HD 32
#define NP 3168    // P + PNET = 32 + 3136
#define IV 100000

typedef unsigned int uint32;
typedef __attribute__((ext_vector_type(8))) short short8;
typedef __attribute__((ext_vector_type(8))) _Float16 half8;
typedef __attribute__((ext_vector_type(4))) float f32x4;
union BF8 { uint32 u[4]; short8 v; };
union HF8 { uint32 u[4]; half8 v; };

__device__ __forceinline__ uint32 f2bf_pack(float x, float y) {
    uint32 ux = __float_as_uint(x);
    uint32 uy = __float_as_uint(y);
    uint32 bx = (ux + 0x7fffu + ((ux >> 16) & 1u)) >> 16;
    uint32 by = (uy + 0x7fffu + ((uy >> 16) & 1u)) >> 16;
    return (by << 16) | (bx & 0xffffu);
}

__device__ __forceinline__ uint32 f2h_pack(float x, float y) {
    __half2 h = __floats2half2_rn(x, y);
    return *(reinterpret_cast<uint32*>(&h));
}

// ---------------------------------------------------------------------------
// Kernel 0: item_emb fp32 -> bf16 packed words (IEB, 32 words/row)
// ---------------------------------------------------------------------------
__global__ __launch_bounds__(256) void k0_cvt(
    const float* __restrict__ src, uint32* __restrict__ dst)
{
    const int i = blockIdx.x * 256 + threadIdx.x;   // < IV*32 = 3.2M exact
    const float2 v = ((const float2*)src)[i];
    dst[i] = f2bf_pack(v.x, v.y);
}

// ---------------------------------------------------------------------------
// Kernel 0b: Wp (64 x NP fp32) -> WpB bf16 packed, layout [n][kw] kw=k-pair
// ---------------------------------------------------------------------------
__global__ __launch_bounds__(256) void k0b_cvt_wp(
    const float* __restrict__ Wp, uint32* __restrict__ WpB)
{
    const int n = blockIdx.x * 256 + threadIdx.x;
    const int kw = blockIdx.y;
    if (n < NP) {
        const float a = Wp[(size_t)(2*kw)*NP + n];
        const float b = Wp[(size_t)(2*kw+1)*NP + n];
        WpB[(size_t)n*32 + kw] = f2bf_pack(a, b);
    }
}

// ---------------------------------------------------------------------------
// Kernel 0c: Wf1/Wf2/Wf3 fp32 -> fp16 packed B-fragment layouts w/ K-padding.
// W1B [208][64] (K=128); W2B [80][112] (K pad 200->224); W3B [64][48] (80->96)
// ---------------------------------------------------------------------------
__global__ __launch_bounds__(256) void k0c_cvt_wf(
    const float* __restrict__ Wf1, const float* __restrict__ Wf2,
    const float* __restrict__ Wf3, uint32* __restrict__ W1B,
    uint32* __restrict__ W2B, uint32* __restrict__ W3B)
{
    const int i = blockIdx.x * 256 + threadIdx.x;
    if (i < 13312) {
        const int n = i >> 6, kw = i & 63;
        W1B[i] = (n < 200) ? f2h_pack(Wf1[(size_t)(2*kw)*200 + n],
                                      Wf1[(size_t)(2*kw+1)*200 + n]) : 0u;
    } else if (i < 22272) {
        const int j = i - 13312, n = j / 112, kw = j % 112;
        W2B[j] = (kw < 100) ? f2h_pack(Wf2[(size_t)(2*kw)*80 + n],
                                       Wf2[(size_t)(2*kw+1)*80 + n]) : 0u;
    } else if (i < 25344) {
        const int j = i - 22272, n = j / 48, kw = j % 48;
        W3B[j] = (kw < 40) ? f2h_pack(Wf3[(size_t)(2*kw)*64 + n],
                                      Wf3[(size_t)(2*kw+1)*64 + n]) : 0u;
    }
}

// ---------------------------------------------------------------------------
// Kernel 1: gathers + attention + pooling.  grid=B, block=256.
// ---------------------------------------------------------------------------
#define HS 33
__global__ __launch_bounds__(256, 4) void k1_gather_attn(
    const uint32* __restrict__ IEB,
    const float* __restrict__ item_emb, const float* __restrict__ user_emb,
    const float* __restrict__ W_if, const float* __restrict__ b_if,
    const float* __restrict__ W_uf, const float* __restrict__ b_uf,
    const float* __restrict__ item_features, const float* __restrict__ user_features,
    const int* __restrict__ user_id, const int* __restrict__ target_item_id,
    const int* __restrict__ hist_id, const int* __restrict__ hist_len,
    const int* __restrict__ pos_fb, const int* __restrict__ pos_mask,
    float* __restrict__ FUE, float* __restrict__ FIE, uint32* __restrict__ PINB)
{
    const int b = blockIdx.x;
    const int t = threadIdx.x;
    const int w = t >> 6;
    const int lane = t & 63;

    __shared__ __align__(16) float tgt[64];
    __shared__ float feats[256];
    __shared__ float ufe[64];
    __shared__ float scoreS[256];
    __shared__ float wred[8];
    __shared__ float part[256];
    __shared__ float part2[256];
    __shared__ float cntw[4];
    __shared__ int   hids[200];
    __shared__ uint32 hist2[200*HS];   // bf16x2 packed rows

    const int hl = hist_len[b];
    if (t < 200) hids[t] = hist_id[(size_t)b*LH + t];
    feats[t] = (t < 128) ? item_features[(size_t)b*128 + t]
                         : user_features[(size_t)b*128 + (t-128)];
    if (t < 64) tgt[t] = item_emb[(size_t)target_item_id[b]*64 + t];
    __syncthreads();

    // ---- Phase A: pure staging, wave w owns rows [w*50, w*50+50) ----
    const int kk = lane & 31;
    const int hf = lane >> 5;
    #pragma unroll
    for (int i = 0; i < 25; i++) {
        const int l = w*50 + i*2 + hf;
        hist2[l*HS + kk] = IEB[(size_t)hids[l]*32 + kk];
    }

    // ---- pos-feedback masked mean (bf16 gather), 25 l's per wave ----
    {
        const int wk = lane >> 1;
        const int comp = lane & 1;
        float acc = 0.f, cnt = 0.f;
        const int l0 = w * 25;
        const int* pid = pos_fb + (size_t)b*LFB;
        const int* pmk = pos_mask + (size_t)b*LFB;
        for (int g = 0; g < 5; g++) {
            const int base = l0 + g*5;
            int m0 = pmk[base+0], m1 = pmk[base+1], m2 = pmk[base+2],
                m3 = pmk[base+3], m4 = pmk[base+4];
            int i0 = pid[base+0], i1 = pid[base+1], i2 = pid[base+2],
                i3 = pid[base+3], i4 = pid[base+4];
            uint32 w0 = IEB[(size_t)i0*32 + wk];
            uint32 w1 = IEB[(size_t)i1*32 + wk];
            uint32 w2 = IEB[(size_t)i2*32 + wk];
            uint32 w3 = IEB[(size_t)i3*32 + wk];
            uint32 w4 = IEB[(size_t)i4*32 + wk];
            float v0 = __uint_as_float(comp ? (w0 & 0xffff0000u) : (w0 << 16));
            float v1 = __uint_as_float(comp ? (w1 & 0xffff0000u) : (w1 << 16));
            float v2 = __uint_as_float(comp ? (w2 & 0xffff0000u) : (w2 << 16));
            float v3 = __uint_as_float(comp ? (w3 & 0xffff0000u) : (w3 << 16));
            float v4 = __uint_as_float(comp ? (w4 & 0xffff0000u) : (w4 << 16));
            float f0 = m0 ? 1.f : 0.f, f1 = m1 ? 1.f : 0.f, f2 = m2 ? 1.f : 0.f,
                  f3 = m3 ? 1.f : 0.f, f4 = m4 ? 1.f : 0.f;
            acc = fmaf(f0, v0, acc); acc = fmaf(f1, v1, acc);
            acc = fmaf(f2, v2, acc); acc = fmaf(f3, v3, acc);
            acc = fmaf(f4, v4, acc);
            cnt += f0 + f1 + f2 + f3 + f4;
        }
        part2[w*64 + lane] = acc;
        if (lane == 0) cntw[w] = cnt;
    }

    // ---- feature embeddings (wave 0: item, wave 1: user) ----
    if (w == 0) {
        float acc = b_if[lane];
        #pragma unroll 4
        for (int k = 0; k < 128; k++) acc = fmaf(feats[k], W_if[k*64 + lane], acc);
        FIE[(size_t)b*64 + lane] = tgt[lane] + 1.f / (1.f + __expf(-acc));
    } else if (w == 1) {
        float acc = b_uf[lane];
        #pragma unroll 4
        for (int k = 0; k < 128; k++) acc = fmaf(feats[128 + k], W_uf[k*64 + lane], acc);
        ufe[lane] = 1.f / (1.f + __expf(-acc));
    }
    __syncthreads();

    // ---- Phase B: per-thread score from LDS row (conflict-free) ----
    float sc = -1e9f;
    if (t < 200) {
        const uint32* hrow = &hist2[t*HS];
        float acc = 0.f;
        #pragma unroll 8
        for (int k2 = 0; k2 < 32; k2++) {
            const uint32 word = hrow[k2];
            const float2 tf = ((const float2*)tgt)[k2];
            acc = fmaf(__uint_as_float(word << 16),        tf.x, acc);
            acc = fmaf(__uint_as_float(word & 0xffff0000u), tf.y, acc);
        }
        if (t < hl) sc = acc * 0.125f;
    }

    // ---- softmax over 200 scores ----
    float m = sc;
    #pragma unroll
    for (int off = 32; off >= 1; off >>= 1) m = fmaxf(m, __shfl_xor(m, off, 64));
    if (lane == 0) wred[w] = m;
    __syncthreads();
    const float mx = fmaxf(fmaxf(wred[0], wred[1]), fmaxf(wred[2], wred[3]));
    const float ev = __expf(sc - mx);
    float s = ev;
    #pragma unroll
    for (int off = 32; off >= 1; off >>= 1) s += __shfl_xor(s, off, 64);
    if (lane == 0) wred[4 + w] = s;
    __syncthreads();
    const float S = wred[4] + wred[5] + wred[6] + wred[7];
    if (t < 200) scoreS[t] = ev / S;
    __syncthreads();

    // ---- pooled from bf16 LDS rows ----
    {
        const int comp = lane & 1;
        const int wk = lane >> 1;
        float acc = 0.f;
        #pragma unroll 5
        for (int l = w*50; l < w*50 + 50; l++) {
            const uint32 word = hist2[l*HS + wk];
            const float hv = __uint_as_float(comp ? (word & 0xffff0000u) : (word << 16));
            acc = fmaf(scoreS[l], hv, acc);
        }
        part[w*64 + lane] = acc;
    }
    __syncthreads();

    if (t < 64) {
        const float c = cntw[0] + cntw[1] + cntw[2] + cntw[3];
        const float pooled = part[t] + part[64+t] + part[128+t] + part[192+t];
        const float pinv = (part2[t] + part2[64+t] + part2[128+t] + part2[192+t]) / c;
        FUE[(size_t)b*64 + t] = user_emb[(size_t)user_id[b]*64 + t] + ufe[t] + pooled;
        const float po = __shfl_xor(pinv, 1, 64);
        if ((t & 1) == 0) PINB[(size_t)b*32 + (t >> 1)] = f2bf_pack(pinv, po);
    }
}

// ---------------------------------------------------------------------------
// Kernel 2: total_prompt = relu(PIN @ Wp + bp) via MFMA bf16.
// ---------------------------------------------------------------------------
__global__ __launch_bounds__(256) void k2_prompt_gemm(
    const uint32* __restrict__ PINB, const uint32* __restrict__ WpB,
    const float* __restrict__ bp, float* __restrict__ TP32,
    uint32* __restrict__ TPN)
{
    __shared__ uint32 As[64*36];
    __shared__ uint32 Bs[128*36];
    __shared__ float bps[128];
    const int t = threadIdx.x;
    const int m0 = blockIdx.y * 64;
    const int n0 = blockIdx.x * 128;

    {
        const int m = t >> 2, kw0 = (t & 3) * 8;
        const uint4 u0 = *(const uint4*)&PINB[(size_t)(m0+m)*32 + kw0];
        const uint4 u1 = *(const uint4*)&PINB[(size_t)(m0+m)*32 + kw0 + 4];
        *(uint4*)&As[m*36 + kw0]     = u0;
        *(uint4*)&As[m*36 + kw0 + 4] = u1;
    }
    {
        const int n = t >> 1, kw0 = (t & 1) * 16;
        const int gn = n0 + n;
        if (gn < NP) {
            #pragma unroll
            for (int j = 0; j < 4; j++) {
                const uint4 u = *(const uint4*)&WpB[(size_t)gn*32 + kw0 + 4*j];
                *(uint4*)&Bs[n*36 + kw0 + 4*j] = u;
            }
        } else {
            #pragma unroll
            for (int j = 0; j < 16; j++) Bs[n*36 + kw0 + j] = 0u;
        }
    }
    if (t < 128) bps[t] = (n0 + t < NP) ? bp[n0 + t] : 0.f;
    __syncthreads();

    const int w = t >> 6, lane = t & 63, ml = lane & 15, q = lane >> 4;

    BF8 a0, a1;
    { uint4 u = *(const uint4*)&As[(w*16+ml)*36 + q*4];      a0.u[0]=u.x; a0.u[1]=u.y; a0.u[2]=u.z; a0.u[3]=u.w; }
    { uint4 u = *(const uint4*)&As[(w*16+ml)*36 + 16 + q*4]; a1.u[0]=u.x; a1.u[1]=u.y; a1.u[2]=u.z; a1.u[3]=u.w; }

    f32x4 c[8];
    #pragma unroll
    for (int nb = 0; nb < 8; nb++) {
        BF8 b0, b1;
        { uint4 u = *(const uint4*)&Bs[(nb*16+ml)*36 + q*4];      b0.u[0]=u.x; b0.u[1]=u.y; b0.u[2]=u.z; b0.u[3]=u.w; }
        { uint4 u = *(const uint4*)&Bs[(nb*16+ml)*36 + 16 + q*4]; b1.u[0]=u.x; b1.u[1]=u.y; b1.u[2]=u.z; b1.u[3]=u.w; }
        f32x4 cc = {0.f, 0.f, 0.f, 0.f};
        cc = __builtin_amdgcn_mfma_f32_16x16x32_bf16(a0.v, b0.v, cc, 0, 0, 0);
        cc = __builtin_amdgcn_mfma_f32_16x16x32_bf16(a1.v, b1.v, cc, 0, 0, 0);
        c[nb] = cc;
    }

    #pragma unroll
    for (int nb = 0; nb < 8; nb++) {
        const int n = n0 + nb*16 + ml;
        const float bv = bps[nb*16 + ml];
        #pragma unroll
        for (int r = 0; r < 4; r++) {
            const int m = m0 + w*16 + q*4 + r;
            const float v = fmaxf(c[nb][r] + bv, 0.f);
            const float vp = __shfl_xor(v, 1, 64);
            if (n < 32) {
                TP32[(size_t)m*32 + n] = v;
            } else if (n < NP && (ml & 1) == 0) {
                TPN[(size_t)m*1568 + ((n - 32) >> 1)] = f2bf_pack(v, vp);
            }
        }
    }
}

// ---------------------------------------------------------------------------
// Kernel 3: prompt hypernetwork via MFMA 16x16x32 bf16.  grid=B, block=256.
// ---------------------------------------------------------------------------
__global__ __launch_bounds__(256) void k3_prompt_mlp(
    const uint32* __restrict__ IEB,
    const int* __restrict__ pos_fb, const int* __restrict__ pos_mask,
    const int* __restrict__ neg_fb, const int* __restrict__ neg_mask,
    const uint32* __restrict__ TPN,
    float* __restrict__ POS_PE, float* __restrict__ out)
{
    const int b = blockIdx.x, t = threadIdx.x;
    const int w = t >> 6, lane = t & 63;
    const int ml = lane & 15, q = lane >> 4;

    __shared__ uint32 w1b[32*36];
    __shared__ uint32 w2b[32*20];
    __shared__ float b1s[32], b2s[32];
    __shared__ float mP[208], mN[208];
    __shared__ int ids[208];
    __shared__ float Hs[4][16*36];
    __shared__ float wps[4][4][16];

    const uint32* pnw = TPN + (size_t)b*1568;
    #pragma unroll
    for (int it = 0; it < 4; it++) {
        const int i = t + 256*it;
        const int n = i >> 5, kw = i & 31;
        const uint32 wa = pnw[kw*32 + (n >> 1)];
        const uint32 wb = pnw[kw*32 + 16 + (n >> 1)];
        const uint32 h0 = (n & 1) ? (wa >> 16) : (wa & 0xffffu);
        const uint32 h1 = (n & 1) ? (wb >> 16) : (wb & 0xffffu);
        w1b[n*36 + kw] = h0 | (h1 << 16);
    }
    #pragma unroll
    for (int it = 0; it < 2; it++) {
        const int i = t + 256*it;
        const int n = i >> 4, kw = i & 15;
        const uint32 wa = pnw[1040 + kw*32 + (n >> 1)];
        const uint32 wb = pnw[1040 + kw*32 + 16 + (n >> 1)];
        const uint32 h0 = (n & 1) ? (wa >> 16) : (wa & 0xffffu);
        const uint32 h1 = (n & 1) ? (wb >> 16) : (wb & 0xffffu);
        w2b[n*20 + kw] = h0 | (h1 << 16);
    }
    if (t < 16) {
        const uint32 wa = pnw[1024 + t];
        b1s[2*t]   = __uint_as_float(wa << 16);
        b1s[2*t+1] = __uint_as_float(wa & 0xffff0000u);
        const uint32 wb = pnw[1552 + t];
        b2s[2*t]   = __uint_as_float(wb << 16);
        b2s[2*t+1] = __uint_as_float(wb & 0xffff0000u);
    }
    if (t < 208) {
        int id = 0; float p = 0.f, nn = 0.f;
        if (t < 100) {
            id = pos_fb[(size_t)b*LFB + t];
            p  = (pos_mask[(size_t)b*LFB + t] != 0) ? 1.f : 0.f;
        } else if (t < 200) {
            const int li = t - 100;
            id = neg_fb[(size_t)b*LFB + li];
            nn = (neg_mask[(size_t)b*LFB + li] != 0) ? 1.f : 0.f;
        }
        ids[t] = id; mP[t] = p; mN[t] = nn;
    }
    __syncthreads();

    BF8 bf100, bf110, bf101, bf111, bf20, bf21;
    {
        uint4 u;
        u = *(const uint4*)&w1b[ml*36 + q*4];            bf100.u[0]=u.x; bf100.u[1]=u.y; bf100.u[2]=u.z; bf100.u[3]=u.w;
        u = *(const uint4*)&w1b[ml*36 + 16 + q*4];       bf110.u[0]=u.x; bf110.u[1]=u.y; bf110.u[2]=u.z; bf110.u[3]=u.w;
        u = *(const uint4*)&w1b[(16+ml)*36 + q*4];       bf101.u[0]=u.x; bf101.u[1]=u.y; bf101.u[2]=u.z; bf101.u[3]=u.w;
        u = *(const uint4*)&w1b[(16+ml)*36 + 16 + q*4];  bf111.u[0]=u.x; bf111.u[1]=u.y; bf111.u[2]=u.z; bf111.u[3]=u.w;
        u = *(const uint4*)&w2b[ml*20 + q*4];            bf20.u[0]=u.x;  bf20.u[1]=u.y;  bf20.u[2]=u.z;  bf20.u[3]=u.w;
        u = *(const uint4*)&w2b[(16+ml)*20 + q*4];       bf21.u[0]=u.x;  bf21.u[1]=u.y;  bf21.u[2]=u.z;  bf21.u[3]=u.w;
    }

    float accP0=0.f, accP1=0.f, accN0=0.f, accN1=0.f;
    float* hsw = Hs[w];

    for (int tile = w; tile < 13; tile += 4) {
        const int g = tile*16 + ml;
        const uint32* rowp = IEB + (size_t)ids[g]*32;
        BF8 a0, a1;
        { uint4 u = *(const uint4*)(rowp + q*4);      a0.u[0]=u.x; a0.u[1]=u.y; a0.u[2]=u.z; a0.u[3]=u.w; }
        { uint4 u = *(const uint4*)(rowp + 16 + q*4); a1.u[0]=u.x; a1.u[1]=u.y; a1.u[2]=u.z; a1.u[3]=u.w; }

        f32x4 c0 = {0.f,0.f,0.f,0.f}, c1 = {0.f,0.f,0.f,0.f};
        c0 = __builtin_amdgcn_mfma_f32_16x16x32_bf16(a0.v, bf100.v, c0, 0, 0, 0);
        c0 = __builtin_amdgcn_mfma_f32_16x16x32_bf16(a1.v, bf110.v, c0, 0, 0, 0);
        c1 = __builtin_amdgcn_mfma_f32_16x16x32_bf16(a0.v, bf101.v, c1, 0, 0, 0);
        c1 = __builtin_amdgcn_mfma_f32_16x16x32_bf16(a1.v, bf111.v, c1, 0, 0, 0);

        #pragma unroll
        for (int r = 0; r < 4; r++) {
            const int row = q*4 + r;
            hsw[row*36 + ml]      = fmaxf(c0[r] + b1s[ml],      0.f);
            hsw[row*36 + 16 + ml] = fmaxf(c1[r] + b1s[16 + ml], 0.f);
        }
        asm volatile("s_waitcnt lgkmcnt(0)" ::: "memory");

        const float4 h0 = *(const float4*)&hsw[ml*36 + q*8];
        const float4 h1 = *(const float4*)&hsw[ml*36 + q*8 + 4];
        BF8 a2;
        a2.u[0] = f2bf_pack(h0.x, h0.y);
        a2.u[1] = f2bf_pack(h0.z, h0.w);
        a2.u[2] = f2bf_pack(h1.x, h1.y);
        a2.u[3] = f2bf_pack(h1.z, h1.w);

        f32x4 d0 = {0.f,0.f,0.f,0.f}, d1 = {0.f,0.f,0.f,0.f};
        d0 = __builtin_amdgcn_mfma_f32_16x16x32_bf16(a2.v, bf20.v, d0, 0, 0, 0);
        d1 = __builtin_amdgcn_mfma_f32_16x16x32_bf16(a2.v, bf21.v, d1, 0, 0, 0);

        #pragma unroll
        for (int r = 0; r < 4; r++) {
            const int g2 = tile*16 + q*4 + r;
            const float o0 = d0[r] + b2s[ml];
            const float o1 = d1[r] + b2s[16 + ml];
            accP0 = fmaf(mP[g2], o0, accP0);
            accP1 = fmaf(mP[g2], o1, accP1);
            accN0 = fmaf(mN[g2], o0, accN0);
            accN1 = fmaf(mN[g2], o1, accN1);
        }
    }

    accP0 += __shfl_xor(accP0, 16, 64); accP0 += __shfl_xor(accP0, 32, 64);
    accP1 += __shfl_xor(accP1, 16, 64); accP1 += __shfl_xor(accP1, 32, 64);
    accN0 += __shfl_xor(accN0, 16, 64); accN0 += __shfl_xor(accN0, 32, 64);
    accN1 += __shfl_xor(accN1, 16, 64); accN1 += __shfl_xor(accN1, 32, 64);
    if (lane < 16) {
        wps[w][0][lane] = accP0;
        wps[w][1][lane] = accP1;
        wps[w][2][lane] = accN0;
        wps[w][3][lane] = accN1;
    }
    __syncthreads();

    if (t < 32) {
        const int nt = t >> 4, p = t & 15;
        const float pp = wps[0][nt][p] + wps[1][nt][p] + wps[2][nt][p] + wps[3][nt][p];
        const float nn = wps[0][2+nt][p] + wps[1][2+nt][p] + wps[2][2+nt][p] + wps[3][2+nt][p];
        POS_PE[(size_t)b*32 + t] = pp;
        const float x = nn - pp;
        out[BN + (size_t)b*32 + t] = fmaxf(x, 0.f) + log1pf(__expf(-fabsf(x)));
    }
}

// ---------------------------------------------------------------------------
// Kernel 4: fused 3-layer fusion MLP + final dot via MFMA fp16.
// grid=256 (1 block/CU), block=256, 16 batches/block.
// Weights staged once in LDS (fp16 B-frag layout), h1/h2 packed fp16 in LDS.
// ---------------------------------------------------------------------------
__global__ __launch_bounds__(256) void k4_fusion(
    const float* __restrict__ FUE, const float* __restrict__ FIE,
    const float* __restrict__ POS_PE, const float* __restrict__ TP32,
    const uint32* __restrict__ W1B, const uint32* __restrict__ W2B,
    const uint32* __restrict__ W3B,
    const float* __restrict__ bf1, const float* __restrict__ bf2,
    float* __restrict__ out)
{
    const int b0 = blockIdx.x * 16;
    const int t = threadIdx.x;
    const int w = t >> 6, lane = t & 63, ml = lane & 15, q = lane >> 4;

    __shared__ uint32 w1s[208*68];   // 56.6 KB  (LD%32=4 -> 2-way, free)
    __shared__ uint32 w2s[80*116];   // 37.1 KB  (LD%32=20)
    __shared__ uint32 w3s[64*52];    // 13.3 KB  (LD%32=20)
    __shared__ uint32 fin[16*68];    // fp16 packed input rows
    __shared__ uint32 h1w[16*116];   // fp16 packed h1 (K pad 224)
    __shared__ uint32 h2w[16*52];    // fp16 packed h2 (K pad 96)
    __shared__ float fuels[16*68];
    __shared__ float b1s[208], b2s[80];
    __shared__ float part4[4][16];

    // ---- stage weights into padded LDS ----
    for (int i = t; i < 13312; i += 256) w1s[(i >> 6)*68 + (i & 63)] = W1B[i];
    for (int i = t; i < 8960; i += 256)  w2s[(i / 112)*116 + (i % 112)] = W2B[i];
    for (int i = t; i < 3072; i += 256)  w3s[(i / 48)*52 + (i % 48)] = W3B[i];

    // ---- stage fin (fp16 packed) + fuel ----
    #pragma unroll
    for (int it = 0; it < 4; it++) {
        const int i = t + 256*it;          // 0..1023
        const int m2 = i >> 6, kw = i & 63;
        const int row = b0 + m2;
        float a, c;
        if (kw < 32)      { const float2 v = *(const float2*)&FIE[(size_t)row*64 + 2*kw];          a = v.x; c = v.y; }
        else if (kw < 48) { const float2 v = *(const float2*)&POS_PE[(size_t)row*32 + 2*kw - 64];  a = v.x; c = v.y; }
        else              { const float2 v = *(const float2*)&TP32[(size_t)row*32 + 2*kw - 96];    a = v.x; c = v.y; }
        fin[m2*68 + kw] = f2h_pack(a, c);
        fuels[m2*68 + kw] = FUE[(size_t)row*64 + kw];
    }
    if (t < 208) b1s[t] = (t < 200) ? bf1[t] : 0.f;
    if (t < 80)  b2s[t] = bf2[t];
    if (t < 128) {
        h1w[(t >> 3)*116 + 104 + (t & 7)] = 0u;   // k 208..223 pad
        h2w[(t >> 3)*52 + 40 + (t & 7)] = 0u;     // k 80..95 pad
    }
    __syncthreads();

    // ---- layer 1: h1 = relu(fin @ Wf1 + bf1), N=208 (13 tiles), K=128 ----
    HF8 a1f[4];
    #pragma unroll
    for (int s = 0; s < 4; s++) {
        const uint4 u = *(const uint4*)&fin[ml*68 + s*16 + q*4];
        a1f[s].u[0] = u.x; a1f[s].u[1] = u.y; a1f[s].u[2] = u.z; a1f[s].u[3] = u.w;
    }
    for (int nt = w; nt < 13; nt += 4) {
        const uint32* wrow = &w1s[(16*nt + ml)*68];
        f32x4 c = {0.f, 0.f, 0.f, 0.f};
        #pragma unroll
        for (int s = 0; s < 4; s++) {
            HF8 bfm;
            const uint4 u = *(const uint4*)&wrow[s*16 + q*4];
            bfm.u[0] = u.x; bfm.u[1] = u.y; bfm.u[2] = u.z; bfm.u[3] = u.w;
            c = __builtin_amdgcn_mfma_f32_16x16x32_f16(a1f[s].v, bfm.v, c, 0, 0, 0);
        }
        const float bv = b1s[16*nt + ml];
        #pragma unroll
        for (int r = 0; r < 4; r++) {
            const float v = fmaxf(c[r] + bv, 0.f);
            const float vp = __shfl_xor(v, 1, 64);
            if ((ml & 1) == 0)
                h1w[(q*4 + r)*116 + 8*nt + (ml >> 1)] = f2h_pack(v, vp);
        }
    }
    __syncthreads();

    // ---- layer 2: h2 = relu(h1 @ Wf2 + bf2), N=80 (5 tiles), K=224 ----
    HF8 a2f[7];
    #pragma unroll
    for (int s = 0; s < 7; s++) {
        const uint4 u = *(const uint4*)&h1w[ml*116 + s*16 + q*4];
        a2f[s].u[0] = u.x; a2f[s].u[1] = u.y; a2f[s].u[2] = u.z; a2f[s].u[3] = u.w;
    }
    for (int nt = w; nt < 5; nt += 4) {
        const uint32* wrow = &w2s[(16*nt + ml)*116];
        f32x4 c = {0.f, 0.f, 0.f, 0.f};
        #pragma unroll
        for (int s = 0; s < 7; s++) {
            HF8 bfm;
            const uint4 u = *(const uint4*)&wrow[s*16 + q*4];
            bfm.u[0] = u.x; bfm.u[1] = u.y; bfm.u[2] = u.z; bfm.u[3] = u.w;
            c = __builtin_amdgcn_mfma_f32_16x16x32_f16(a2f[s].v, bfm.v, c, 0, 0, 0);
        }
        const float bv = b2s[16*nt + ml];
        #pragma unroll
        for (int r = 0; r < 4; r++) {
            const float v = fmaxf(c[r] + bv, 0.f);
            const float vp = __shfl_xor(v, 1, 64);
            if ((ml & 1) == 0)
                h2w[(q*4 + r)*52 + 8*nt + (ml >> 1)] = f2h_pack(v, vp);
        }
    }
    __syncthreads();

    // ---- layer 3: fused = h2 @ Wf3 (no bias/relu); dot with fuel ----
    {
        const int nt = w;                  // 4 waves, 4 N-tiles of 16
        const uint32* wrow = &w3s[(16*nt + ml)*52];
        f32x4 c = {0.f, 0.f, 0.f, 0.f};
        #pragma unroll
        for (int s = 0; s < 3; s++) {
            HF8 afm, bfm;
            const uint4 ua = *(const uint4*)&h2w[ml*52 + s*16 + q*4];
            afm.u[0] = ua.x; afm.u[1] = ua.y; afm.u[2] = ua.z; afm.u[3] = ua.w;
            const uint4 ub = *(const uint4*)&wrow[s*16 + q*4];
            bfm.u[0] = ub.x; bfm.u[1] = ub.y; bfm.u[2] = ub.z; bfm.u[3] = ub.w;
            c = __builtin_amdgcn_mfma_f32_16x16x32_f16(afm.v, bfm.v, c, 0, 0, 0);
        }
        #pragma unroll
        for (int r = 0; r < 4; r++) {
            float p = c[r] * fuels[(q*4 + r)*68 + 16*nt + ml];
            p += __shfl_xor(p, 1, 64);
            p += __shfl_xor(p, 2, 64);
            p += __shfl_xor(p, 4, 64);
            p += __shfl_xor(p, 8, 64);
            if (ml == 0) part4[w][q*4 + r] = p;
        }
    }
    __syncthreads();

    if (t < 16) out[b0 + t] = part4[0][t] + part4[1][t] + part4[2][t] + part4[3][t];
}

// ---------------------------------------------------------------------------
extern "C" void kernel_launch(void* const* d_in, const int* in_sizes, int n_in,
                              void* d_out, int out_size, void* d_ws, size_t ws_size,
                              hipStream_t stream)
{
    const float* item_emb       = (const float*)d_in[0];
    const float* user_emb       = (const float*)d_in[1];
    const float* W_if           = (const float*)d_in[2];
    const float* b_if           = (const float*)d_in[3];
    const float* W_uf           = (const float*)d_in[4];
    const float* b_uf           = (const float*)d_in[5];
    const float* Wp             = (const float*)d_in[6];
    const float* bp             = (const float*)d_in[7];
    const float* Wf1            = (const float*)d_in[8];
    const float* bf1            = (const float*)d_in[9];
    const float* Wf2            = (const float*)d_in[10];
    const float* bf2            = (const float*)d_in[11];
    const float* Wf3            = (const float*)d_in[12];
    const float* item_features  = (const float*)d_in[13];
    const float* user_features  = (const float*)d_in[14];
    const int*   user_id        = (const int*)d_in[15];
    const int*   target_item_id = (const int*)d_in[16];
    const int*   history_item_id= (const int*)d_in[17];
    const int*   history_len    = (const int*)d_in[18];
    const int*   pos_fb         = (const int*)d_in[19];
    const int*   pos_mask       = (const int*)d_in[20];
    const int*   neg_fb         = (const int*)d_in[21];
    const int*   neg_mask       = (const int*)d_in[22];

    float* out = (float*)d_out;
    float* ws  = (float*)d_ws;

    uint32* IEB  = (uint32*)ws;                       // IV*32
    uint32* WpB  = IEB + (size_t)IV*32;               // NP*32
    uint32* W1B  = WpB + (size_t)NP*32;               // 13312
    uint32* W2B  = W1B + 13312;                       // 8960
    uint32* W3B  = W2B + 8960;                        // 3072
    uint32* PINB = W3B + 3072;                        // BN*32
    float*  FUE  = (float*)(PINB + (size_t)BN*32);
    float*  FIE  = FUE + (size_t)BN*64;
    float*  TP32 = FIE + (size_t)BN*64;               // BN*32
    uint32* TPN  = (uint32*)(TP32 + (size_t)BN*32);   // BN*1568
    float*  PPE  = (float*)(TPN + (size_t)BN*1568);

    k0_cvt<<<dim3(IV*32/256), dim3(256), 0, stream>>>(item_emb, IEB);
    k0b_cvt_wp<<<dim3(13, 32), dim3(256), 0, stream>>>(Wp, WpB);
    k0c_cvt_wf<<<dim3(99), dim3(256), 0, stream>>>(Wf1, Wf2, Wf3, W1B, W2B, W3B);

    k1_gather_attn<<<dim3(BN), dim3(256), 0, stream>>>(
        IEB, item_emb, user_emb, W_if, b_if, W_uf, b_uf,
        item_features, user_features, user_id, target_item_id,
        history_item_id, history_len, pos_fb, pos_mask,
        FUE, FIE, PINB);

    k2_prompt_gemm<<<dim3(25, 64), dim3(256), 0, stream>>>(PINB, WpB, bp, TP32, TPN);

    k3_prompt_mlp<<<dim3(BN), dim3(256), 0, stream>>>(
        IEB, pos_fb, pos_mask, neg_fb, neg_mask, TPN, PPE, out);

    k4_fusion<<<dim3(BN/16), dim3(256), 0, stream>>>(
        FUE, FIE, PPE, TP32, W1B, W2B, W3B, bf1, bf2, out);
}

// Round 7
// 261.934 us; speedup vs baseline: 1.8955x; 1.0100x over previous
//
#include <hip/hip_runtime.h>
#include <hip/hip_bf16.h>
#include <hip/hip_fp16.h>
#include <math.h>

#define BN 4096
#define LH 200
#define LFB 100
#define ED 64
#define PD 32
#define HD 32
#define NP 3168    // P + PNET = 32 + 3136
#define IV 100000

typedef unsigned int uint32;
typedef __attribute__((ext_vector_type(8))) short short8;
typedef __attribute__((ext_vector_type(8))) _Float16 half8;
typedef __attribute__((ext_vector_type(4))) float f32x4;
union BF8 { uint32 u[4]; short8 v; };
union HF8 { uint32 u[4]; half8 v; };

__device__ __forceinline__ uint32 f2bf_pack(float x, float y) {
    uint32 ux = __float_as_uint(x);
    uint32 uy = __float_as_uint(y);
    uint32 bx = (ux + 0x7fffu + ((ux >> 16) & 1u)) >> 16;
    uint32 by = (uy + 0x7fffu + ((uy >> 16) & 1u)) >> 16;
    return (by << 16) | (bx & 0xffffu);
}

__device__ __forceinline__ uint32 f2h_pack(float x, float y) {
    __half2 h = __floats2half2_rn(x, y);
    return *(reinterpret_cast<uint32*>(&h));
}

// ---------------------------------------------------------------------------
// Kernel 0: item_emb fp32 -> bf16 packed words (IEB, 32 words/row)
// ---------------------------------------------------------------------------
__global__ __launch_bounds__(256) void k0_cvt(
    const float* __restrict__ src, uint32* __restrict__ dst)
{
    const int i = blockIdx.x * 256 + threadIdx.x;   // < IV*32 = 3.2M exact
    const float2 v = ((const float2*)src)[i];
    dst[i] = f2bf_pack(v.x, v.y);
}

// ---------------------------------------------------------------------------
// Kernel 0b: Wp (64 x NP fp32) -> WpB bf16 packed, layout [n][kw] kw=k-pair
// ---------------------------------------------------------------------------
__global__ __launch_bounds__(256) void k0b_cvt_wp(
    const float* __restrict__ Wp, uint32* __restrict__ WpB)
{
    const int n = blockIdx.x * 256 + threadIdx.x;
    const int kw = blockIdx.y;
    if (n < NP) {
        const float a = Wp[(size_t)(2*kw)*NP + n];
        const float b = Wp[(size_t)(2*kw+1)*NP + n];
        WpB[(size_t)n*32 + kw] = f2bf_pack(a, b);
    }
}

// ---------------------------------------------------------------------------
// Kernel 0c: Wf1/Wf2/Wf3 fp32 -> fp16 packed B-fragment layouts w/ K-padding.
// ---------------------------------------------------------------------------
__global__ __launch_bounds__(256) void k0c_cvt_wf(
    const float* __restrict__ Wf1, const float* __restrict__ Wf2,
    const float* __restrict__ Wf3, uint32* __restrict__ W1B,
    uint32* __restrict__ W2B, uint32* __restrict__ W3B)
{
    const int i = blockIdx.x * 256 + threadIdx.x;
    if (i < 13312) {
        const int n = i >> 6, kw = i & 63;
        W1B[i] = (n < 200) ? f2h_pack(Wf1[(size_t)(2*kw)*200 + n],
                                      Wf1[(size_t)(2*kw+1)*200 + n]) : 0u;
    } else if (i < 22272) {
        const int j = i - 13312, n = j / 112, kw = j % 112;
        W2B[j] = (kw < 100) ? f2h_pack(Wf2[(size_t)(2*kw)*80 + n],
                                       Wf2[(size_t)(2*kw+1)*80 + n]) : 0u;
    } else if (i < 25344) {
        const int j = i - 22272, n = j / 48, kw = j % 48;
        W3B[j] = (kw < 40) ? f2h_pack(Wf3[(size_t)(2*kw)*64 + n],
                                      Wf3[(size_t)(2*kw+1)*64 + n]) : 0u;
    }
}

// ---------------------------------------------------------------------------
// Kernel 1: gathers + attention + pooling.  grid=B, block=256.
// Dynamic bounds: only history_len rows staged/pooled; pos-feedback mean
// over ballot-compacted active list (exact math, ~half the gather lines).
// ---------------------------------------------------------------------------
#define HS 33
__global__ __launch_bounds__(256, 4) void k1_gather_attn(
    const uint32* __restrict__ IEB,
    const float* __restrict__ item_emb, const float* __restrict__ user_emb,
    const float* __restrict__ W_if, const float* __restrict__ b_if,
    const float* __restrict__ W_uf, const float* __restrict__ b_uf,
    const float* __restrict__ item_features, const float* __restrict__ user_features,
    const int* __restrict__ user_id, const int* __restrict__ target_item_id,
    const int* __restrict__ hist_id, const int* __restrict__ hist_len,
    const int* __restrict__ pos_fb, const int* __restrict__ pos_mask,
    float* __restrict__ FUE, float* __restrict__ FIE, uint32* __restrict__ PINB)
{
    const int b = blockIdx.x;
    const int t = threadIdx.x;
    const int w = t >> 6;
    const int lane = t & 63;

    __shared__ __align__(16) float tgt[64];
    __shared__ float feats[256];
    __shared__ float ufe[64];
    __shared__ float scoreS[256];
    __shared__ float wred[8];
    __shared__ float part[256];
    __shared__ float part2[256];
    __shared__ int   hids[200];
    __shared__ int   cpi[104];
    __shared__ int   ptot[2];
    __shared__ uint32 hist2[200*HS];   // bf16x2 packed rows

    const int hl = hist_len[b];
    if (t < 200) hids[t] = hist_id[(size_t)b*LH + t];
    feats[t] = (t < 128) ? item_features[(size_t)b*128 + t]
                         : user_features[(size_t)b*128 + (t-128)];
    if (t < 64) tgt[t] = item_emb[(size_t)target_item_id[b]*64 + t];

    bool myAct = false; int myPid = 0;
    if (t < LFB) {
        myAct = pos_mask[(size_t)b*LFB + t] != 0;
        myPid = pos_fb[(size_t)b*LFB + t];
    }
    __syncthreads();   // sync0: tgt/hids/feats

    // ---- Phase A: staging, only rows l < hl (interleaved partition) ----
    const int kk = lane & 31;
    const int hf = lane >> 5;
    for (int l = w*2 + hf; l < hl; l += 8)
        hist2[l*HS + kk] = IEB[(size_t)hids[l]*32 + kk];

    // ---- pos-feedback compaction ballot (waves 0,1) ----
    int pre = 0;
    if (w < 2) {
        const unsigned long long bal = __ballot(myAct);
        pre = __popcll(bal & ((1ull << lane) - 1ull));
        if (lane == 0) ptot[w] = __popcll(bal);
    }
    __syncthreads();   // sync1: hist2, ptot visible

    const int nP = ptot[0] + ptot[1];
    if (w < 2 && myAct) cpi[((w == 1) ? ptot[0] : 0) + pre] = myPid;

    // ---- scores from LDS rows (t < hl) ----
    float sc = -1e9f;
    if (t < hl) {
        const uint32* hrow = &hist2[t*HS];
        float acc = 0.f;
        #pragma unroll 8
        for (int k2 = 0; k2 < 32; k2++) {
            const uint32 word = hrow[k2];
            const float2 tf = ((const float2*)tgt)[k2];
            acc = fmaf(__uint_as_float(word << 16),         tf.x, acc);
            acc = fmaf(__uint_as_float(word & 0xffff0000u), tf.y, acc);
        }
        sc = acc * 0.125f;
    }
    float m = sc;
    #pragma unroll
    for (int off = 32; off >= 1; off >>= 1) m = fmaxf(m, __shfl_xor(m, off, 64));
    if (lane == 0) wred[w] = m;
    __syncthreads();   // sync2: wred(max), cpi visible

    const float mx = fmaxf(fmaxf(wred[0], wred[1]), fmaxf(wred[2], wred[3]));
    const float ev = __expf(sc - mx);

    // ---- pos-mean gather over compacted list (loads overlap softmax) ----
    const int wk = lane >> 1;
    const int comp = lane & 1;
    {
        float pacc = 0.f;
        for (int i = w; i < nP; i += 4) {
            const uint32 wd = IEB[(size_t)cpi[i]*32 + wk];
            pacc += __uint_as_float(comp ? (wd & 0xffff0000u) : (wd << 16));
        }
        part2[w*64 + lane] = pacc;
    }

    float s = ev;
    #pragma unroll
    for (int off = 32; off >= 1; off >>= 1) s += __shfl_xor(s, off, 64);
    if (lane == 0) wred[4 + w] = s;

    // ---- feature embeddings (wave 0: item, wave 1: user) ----
    if (w == 0) {
        float acc = b_if[lane];
        #pragma unroll 4
        for (int k = 0; k < 128; k++) acc = fmaf(feats[k], W_if[k*64 + lane], acc);
        FIE[(size_t)b*64 + lane] = tgt[lane] + 1.f / (1.f + __expf(-acc));
    } else if (w == 1) {
        float acc = b_uf[lane];
        #pragma unroll 4
        for (int k = 0; k < 128; k++) acc = fmaf(feats[128 + k], W_uf[k*64 + lane], acc);
        ufe[lane] = 1.f / (1.f + __expf(-acc));
    }
    __syncthreads();   // sync3: wred sums

    const float S = wred[4] + wred[5] + wred[6] + wred[7];
    if (t < 200) scoreS[t] = ev / S;
    __syncthreads();   // sync4: attn visible

    // ---- pooled over valid rows only (interleaved) ----
    {
        float acc = 0.f;
        for (int l = w; l < hl; l += 4) {
            const uint32 word = hist2[l*HS + wk];
            const float hv = __uint_as_float(comp ? (word & 0xffff0000u) : (word << 16));
            acc = fmaf(scoreS[l], hv, acc);
        }
        part[w*64 + lane] = acc;
    }
    __syncthreads();   // sync5

    if (t < 64) {
        const float pooled = part[t] + part[64+t] + part[128+t] + part[192+t];
        const float pinv = (part2[t] + part2[64+t] + part2[128+t] + part2[192+t]) / (float)nP;
        FUE[(size_t)b*64 + t] = user_emb[(size_t)user_id[b]*64 + t] + ufe[t] + pooled;
        const float po = __shfl_xor(pinv, 1, 64);
        if ((t & 1) == 0) PINB[(size_t)b*32 + (t >> 1)] = f2bf_pack(pinv, po);
    }
}

// ---------------------------------------------------------------------------
// Kernel 2: total_prompt = relu(PIN @ Wp + bp) via MFMA bf16.
// ---------------------------------------------------------------------------
__global__ __launch_bounds__(256) void k2_prompt_gemm(
    const uint32* __restrict__ PINB, const uint32* __restrict__ WpB,
    const float* __restrict__ bp, float* __restrict__ TP32,
    uint32* __restrict__ TPN)
{
    __shared__ uint32 As[64*36];
    __shared__ uint32 Bs[128*36];
    __shared__ float bps[128];
    const int t = threadIdx.x;
    const int m0 = blockIdx.y * 64;
    const int n0 = blockIdx.x * 128;

    {
        const int m = t >> 2, kw0 = (t & 3) * 8;
        const uint4 u0 = *(const uint4*)&PINB[(size_t)(m0+m)*32 + kw0];
        const uint4 u1 = *(const uint4*)&PINB[(size_t)(m0+m)*32 + kw0 + 4];
        *(uint4*)&As[m*36 + kw0]     = u0;
        *(uint4*)&As[m*36 + kw0 + 4] = u1;
    }
    {
        const int n = t >> 1, kw0 = (t & 1) * 16;
        const int gn = n0 + n;
        if (gn < NP) {
            #pragma unroll
            for (int j = 0; j < 4; j++) {
                const uint4 u = *(const uint4*)&WpB[(size_t)gn*32 + kw0 + 4*j];
                *(uint4*)&Bs[n*36 + kw0 + 4*j] = u;
            }
        } else {
            #pragma unroll
            for (int j = 0; j < 16; j++) Bs[n*36 + kw0 + j] = 0u;
        }
    }
    if (t < 128) bps[t] = (n0 + t < NP) ? bp[n0 + t] : 0.f;
    __syncthreads();

    const int w = t >> 6, lane = t & 63, ml = lane & 15, q = lane >> 4;

    BF8 a0, a1;
    { uint4 u = *(const uint4*)&As[(w*16+ml)*36 + q*4];      a0.u[0]=u.x; a0.u[1]=u.y; a0.u[2]=u.z; a0.u[3]=u.w; }
    { uint4 u = *(const uint4*)&As[(w*16+ml)*36 + 16 + q*4]; a1.u[0]=u.x; a1.u[1]=u.y; a1.u[2]=u.z; a1.u[3]=u.w; }

    f32x4 c[8];
    #pragma unroll
    for (int nb = 0; nb < 8; nb++) {
        BF8 b0, b1;
        { uint4 u = *(const uint4*)&Bs[(nb*16+ml)*36 + q*4];      b0.u[0]=u.x; b0.u[1]=u.y; b0.u[2]=u.z; b0.u[3]=u.w; }
        { uint4 u = *(const uint4*)&Bs[(nb*16+ml)*36 + 16 + q*4]; b1.u[0]=u.x; b1.u[1]=u.y; b1.u[2]=u.z; b1.u[3]=u.w; }
        f32x4 cc = {0.f, 0.f, 0.f, 0.f};
        cc = __builtin_amdgcn_mfma_f32_16x16x32_bf16(a0.v, b0.v, cc, 0, 0, 0);
        cc = __builtin_amdgcn_mfma_f32_16x16x32_bf16(a1.v, b1.v, cc, 0, 0, 0);
        c[nb] = cc;
    }

    #pragma unroll
    for (int nb = 0; nb < 8; nb++) {
        const int n = n0 + nb*16 + ml;
        const float bv = bps[nb*16 + ml];
        #pragma unroll
        for (int r = 0; r < 4; r++) {
            const int m = m0 + w*16 + q*4 + r;
            const float v = fmaxf(c[nb][r] + bv, 0.f);
            const float vp = __shfl_xor(v, 1, 64);
            if (n < 32) {
                TP32[(size_t)m*32 + n] = v;
            } else if (n < NP && (ml & 1) == 0) {
                TPN[(size_t)m*1568 + ((n - 32) >> 1)] = f2bf_pack(v, vp);
            }
        }
    }
}

// ---------------------------------------------------------------------------
// Kernel 3: prompt hypernetwork via MFMA 16x16x32 bf16.  grid=B, block=256.
// Active pos/neg items ballot-compacted into one dense row list: masks
// become position predicates; tile count (R+15)/16 ~ halves gathers+MFMA.
// ---------------------------------------------------------------------------
__global__ __launch_bounds__(256) void k3_prompt_mlp(
    const uint32* __restrict__ IEB,
    const int* __restrict__ pos_fb, const int* __restrict__ pos_mask,
    const int* __restrict__ neg_fb, const int* __restrict__ neg_mask,
    const uint32* __restrict__ TPN,
    float* __restrict__ POS_PE, float* __restrict__ out)
{
    const int b = blockIdx.x, t = threadIdx.x;
    const int w = t >> 6, lane = t & 63;
    const int ml = lane & 15, q = lane >> 4;

    __shared__ uint32 w1b[32*36];
    __shared__ uint32 w2b[32*20];
    __shared__ float b1s[32], b2s[32];
    __shared__ float mPs[208], mNs[208];
    __shared__ int cids[208];
    __shared__ int tot[4];
    __shared__ float Hs[4][16*36];
    __shared__ float wps[4][4][16];

    // per-thread id/mask + ballot compaction counts
    bool act = false; int id = 0;
    if (t < LFB) {
        act = pos_mask[(size_t)b*LFB + t] != 0;
        id  = pos_fb[(size_t)b*LFB + t];
    } else if (t >= 128 && t < 128 + LFB) {
        act = neg_mask[(size_t)b*LFB + (t-128)] != 0;
        id  = neg_fb[(size_t)b*LFB + (t-128)];
    }
    const unsigned long long bal = __ballot(act);
    const int pre = __popcll(bal & ((1ull << lane) - 1ull));
    if (lane == 0) tot[w] = __popcll(bal);
    if (t < 208) cids[t] = 0;

    const uint32* pnw = TPN + (size_t)b*1568;
    #pragma unroll
    for (int it = 0; it < 4; it++) {
        const int i = t + 256*it;
        const int n = i >> 5, kw = i & 31;
        const uint32 wa = pnw[kw*32 + (n >> 1)];
        const uint32 wb = pnw[kw*32 + 16 + (n >> 1)];
        const uint32 h0 = (n & 1) ? (wa >> 16) : (wa & 0xffffu);
        const uint32 h1 = (n & 1) ? (wb >> 16) : (wb & 0xffffu);
        w1b[n*36 + kw] = h0 | (h1 << 16);
    }
    #pragma unroll
    for (int it = 0; it < 2; it++) {
        const int i = t + 256*it;
        const int n = i >> 4, kw = i & 15;
        const uint32 wa = pnw[1040 + kw*32 + (n >> 1)];
        const uint32 wb = pnw[1040 + kw*32 + 16 + (n >> 1)];
        const uint32 h0 = (n & 1) ? (wa >> 16) : (wa & 0xffffu);
        const uint32 h1 = (n & 1) ? (wb >> 16) : (wb & 0xffffu);
        w2b[n*20 + kw] = h0 | (h1 << 16);
    }
    if (t < 16) {
        const uint32 wa = pnw[1024 + t];
        b1s[2*t]   = __uint_as_float(wa << 16);
        b1s[2*t+1] = __uint_as_float(wa & 0xffff0000u);
        const uint32 wb = pnw[1552 + t];
        b2s[2*t]   = __uint_as_float(wb << 16);
        b2s[2*t+1] = __uint_as_float(wb & 0xffff0000u);
    }
    __syncthreads();   // sync1: tot, cids-zero, w1b/w2b/biases visible

    const int nP = tot[0] + tot[1];
    const int nN = tot[2] + tot[3];
    const int R  = nP + nN;
    const int T  = (R + 15) >> 4;
    {
        int base = 0;
        if (w == 1) base = tot[0];
        else if (w == 2) base = nP;
        else if (w == 3) base = nP + tot[2];
        if (act) cids[base + pre] = id;
    }
    if (t < 208) {
        mPs[t] = (t < nP) ? 1.f : 0.f;
        mNs[t] = (t >= nP && t < R) ? 1.f : 0.f;
    }

    // hoist B fragments (reads w1b/w2b, ready after sync1)
    BF8 bf100, bf110, bf101, bf111, bf20, bf21;
    {
        uint4 u;
        u = *(const uint4*)&w1b[ml*36 + q*4];            bf100.u[0]=u.x; bf100.u[1]=u.y; bf100.u[2]=u.z; bf100.u[3]=u.w;
        u = *(const uint4*)&w1b[ml*36 + 16 + q*4];       bf110.u[0]=u.x; bf110.u[1]=u.y; bf110.u[2]=u.z; bf110.u[3]=u.w;
        u = *(const uint4*)&w1b[(16+ml)*36 + q*4];       bf101.u[0]=u.x; bf101.u[1]=u.y; bf101.u[2]=u.z; bf101.u[3]=u.w;
        u = *(const uint4*)&w1b[(16+ml)*36 + 16 + q*4];  bf111.u[0]=u.x; bf111.u[1]=u.y; bf111.u[2]=u.z; bf111.u[3]=u.w;
        u = *(const uint4*)&w2b[ml*20 + q*4];            bf20.u[0]=u.x;  bf20.u[1]=u.y;  bf20.u[2]=u.z;  bf20.u[3]=u.w;
        u = *(const uint4*)&w2b[(16+ml)*20 + q*4];       bf21.u[0]=u.x;  bf21.u[1]=u.y;  bf21.u[2]=u.z;  bf21.u[3]=u.w;
    }
    __syncthreads();   // sync2: cids, mPs/mNs visible

    float accP0=0.f, accP1=0.f, accN0=0.f, accN1=0.f;
    float* hsw = Hs[w];

    for (int tile = w; tile < T; tile += 4) {
        const int g = tile*16 + ml;
        const uint32* rowp = IEB + (size_t)cids[g]*32;
        BF8 a0, a1;
        { uint4 u = *(const uint4*)(rowp + q*4);      a0.u[0]=u.x; a0.u[1]=u.y; a0.u[2]=u.z; a0.u[3]=u.w; }
        { uint4 u = *(const uint4*)(rowp + 16 + q*4); a1.u[0]=u.x; a1.u[1]=u.y; a1.u[2]=u.z; a1.u[3]=u.w; }

        f32x4 c0 = {0.f,0.f,0.f,0.f}, c1 = {0.f,0.f,0.f,0.f};
        c0 = __builtin_amdgcn_mfma_f32_16x16x32_bf16(a0.v, bf100.v, c0, 0, 0, 0);
        c0 = __builtin_amdgcn_mfma_f32_16x16x32_bf16(a1.v, bf110.v, c0, 0, 0, 0);
        c1 = __builtin_amdgcn_mfma_f32_16x16x32_bf16(a0.v, bf101.v, c1, 0, 0, 0);
        c1 = __builtin_amdgcn_mfma_f32_16x16x32_bf16(a1.v, bf111.v, c1, 0, 0, 0);

        #pragma unroll
        for (int r = 0; r < 4; r++) {
            const int row = q*4 + r;
            hsw[row*36 + ml]      = fmaxf(c0[r] + b1s[ml],      0.f);
            hsw[row*36 + 16 + ml] = fmaxf(c1[r] + b1s[16 + ml], 0.f);
        }
        asm volatile("s_waitcnt lgkmcnt(0)" ::: "memory");

        const float4 h0 = *(const float4*)&hsw[ml*36 + q*8];
        const float4 h1 = *(const float4*)&hsw[ml*36 + q*8 + 4];
        BF8 a2;
        a2.u[0] = f2bf_pack(h0.x, h0.y);
        a2.u[1] = f2bf_pack(h0.z, h0.w);
        a2.u[2] = f2bf_pack(h1.x, h1.y);
        a2.u[3] = f2bf_pack(h1.z, h1.w);

        f32x4 d0 = {0.f,0.f,0.f,0.f}, d1 = {0.f,0.f,0.f,0.f};
        d0 = __builtin_amdgcn_mfma_f32_16x16x32_bf16(a2.v, bf20.v, d0, 0, 0, 0);
        d1 = __builtin_amdgcn_mfma_f32_16x16x32_bf16(a2.v, bf21.v, d1, 0, 0, 0);

        #pragma unroll
        for (int r = 0; r < 4; r++) {
            const int g2 = tile*16 + q*4 + r;
            const float o0 = d0[r] + b2s[ml];
            const float o1 = d1[r] + b2s[16 + ml];
            accP0 = fmaf(mPs[g2], o0, accP0);
            accP1 = fmaf(mPs[g2], o1, accP1);
            accN0 = fmaf(mNs[g2], o0, accN0);
            accN1 = fmaf(mNs[g2], o1, accN1);
        }
    }

    accP0 += __shfl_xor(accP0, 16, 64); accP0 += __shfl_xor(accP0, 32, 64);
    accP1 += __shfl_xor(accP1, 16, 64); accP1 += __shfl_xor(accP1, 32, 64);
    accN0 += __shfl_xor(accN0, 16, 64); accN0 += __shfl_xor(accN0, 32, 64);
    accN1 += __shfl_xor(accN1, 16, 64); accN1 += __shfl_xor(accN1, 32, 64);
    if (lane < 16) {
        wps[w][0][lane] = accP0;
        wps[w][1][lane] = accP1;
        wps[w][2][lane] = accN0;
        wps[w][3][lane] = accN1;
    }
    __syncthreads();

    if (t < 32) {
        const int nt = t >> 4, p = t & 15;
        const float pp = wps[0][nt][p] + wps[1][nt][p] + wps[2][nt][p] + wps[3][nt][p];
        const float nn = wps[0][2+nt][p] + wps[1][2+nt][p] + wps[2][2+nt][p] + wps[3][2+nt][p];
        POS_PE[(size_t)b*32 + t] = pp;
        const float x = nn - pp;
        out[BN + (size_t)b*32 + t] = fmaxf(x, 0.f) + log1pf(__expf(-fabsf(x)));
    }
}

// ---------------------------------------------------------------------------
// Kernel 4: fused 3-layer fusion MLP + final dot via MFMA fp16.
// ---------------------------------------------------------------------------
__global__ __launch_bounds__(256) void k4_fusion(
    const float* __restrict__ FUE, const float* __restrict__ FIE,
    const float* __restrict__ POS_PE, const float* __restrict__ TP32,
    const uint32* __restrict__ W1B, const uint32* __restrict__ W2B,
    const uint32* __restrict__ W3B,
    const float* __restrict__ bf1, const float* __restrict__ bf2,
    float* __restrict__ out)
{
    const int b0 = blockIdx.x * 16;
    const int t = threadIdx.x;
    const int w = t >> 6, lane = t & 63, ml = lane & 15, q = lane >> 4;

    __shared__ uint32 w1s[208*68];
    __shared__ uint32 w2s[80*116];
    __shared__ uint32 w3s[64*52];
    __shared__ uint32 fin[16*68];
    __shared__ uint32 h1w[16*116];
    __shared__ uint32 h2w[16*52];
    __shared__ float fuels[16*68];
    __shared__ float b1s[208], b2s[80];
    __shared__ float part4[4][16];

    for (int i = t; i < 13312; i += 256) w1s[(i >> 6)*68 + (i & 63)] = W1B[i];
    for (int i = t; i < 8960; i += 256)  w2s[(i / 112)*116 + (i % 112)] = W2B[i];
    for (int i = t; i < 3072; i += 256)  w3s[(i / 48)*52 + (i % 48)] = W3B[i];

    #pragma unroll
    for (int it = 0; it < 4; it++) {
        const int i = t + 256*it;
        const int m2 = i >> 6, kw = i & 63;
        const int row = b0 + m2;
        float a, c;
        if (kw < 32)      { const float2 v = *(const float2*)&FIE[(size_t)row*64 + 2*kw];          a = v.x; c = v.y; }
        else if (kw < 48) { const float2 v = *(const float2*)&POS_PE[(size_t)row*32 + 2*kw - 64];  a = v.x; c = v.y; }
        else              { const float2 v = *(const float2*)&TP32[(size_t)row*32 + 2*kw - 96];    a = v.x; c = v.y; }
        fin[m2*68 + kw] = f2h_pack(a, c);
        fuels[m2*68 + kw] = FUE[(size_t)row*64 + kw];
    }
    if (t < 208) b1s[t] = (t < 200) ? bf1[t] : 0.f;
    if (t < 80)  b2s[t] = bf2[t];
    if (t < 128) {
        h1w[(t >> 3)*116 + 104 + (t & 7)] = 0u;
        h2w[(t >> 3)*52 + 40 + (t & 7)] = 0u;
    }
    __syncthreads();

    HF8 a1f[4];
    #pragma unroll
    for (int s = 0; s < 4; s++) {
        const uint4 u = *(const uint4*)&fin[ml*68 + s*16 + q*4];
        a1f[s].u[0] = u.x; a1f[s].u[1] = u.y; a1f[s].u[2] = u.z; a1f[s].u[3] = u.w;
    }
    for (int nt = w; nt < 13; nt += 4) {
        const uint32* wrow = &w1s[(16*nt + ml)*68];
        f32x4 c = {0.f, 0.f, 0.f, 0.f};
        #pragma unroll
        for (int s = 0; s < 4; s++) {
            HF8 bfm;
            const uint4 u = *(const uint4*)&wrow[s*16 + q*4];
            bfm.u[0] = u.x; bfm.u[1] = u.y; bfm.u[2] = u.z; bfm.u[3] = u.w;
            c = __builtin_amdgcn_mfma_f32_16x16x32_f16(a1f[s].v, bfm.v, c, 0, 0, 0);
        }
        const float bv = b1s[16*nt + ml];
        #pragma unroll
        for (int r = 0; r < 4; r++) {
            const float v = fmaxf(c[r] + bv, 0.f);
            const float vp = __shfl_xor(v, 1, 64);
            if ((ml & 1) == 0)
                h1w[(q*4 + r)*116 + 8*nt + (ml >> 1)] = f2h_pack(v, vp);
        }
    }
    __syncthreads();

    HF8 a2f[7];
    #pragma unroll
    for (int s = 0; s < 7; s++) {
        const uint4 u = *(const uint4*)&h1w[ml*116 + s*16 + q*4];
        a2f[s].u[0] = u.x; a2f[s].u[1] = u.y; a2f[s].u[2] = u.z; a2f[s].u[3] = u.w;
    }
    for (int nt = w; nt < 5; nt += 4) {
        const uint32* wrow = &w2s[(16*nt + ml)*116];
        f32x4 c = {0.f, 0.f, 0.f, 0.f};
        #pragma unroll
        for (int s = 0; s < 7; s++) {
            HF8 bfm;
            const uint4 u = *(const uint4*)&wrow[s*16 + q*4];
            bfm.u[0] = u.x; bfm.u[1] = u.y; bfm.u[2] = u.z; bfm.u[3] = u.w;
            c = __builtin_amdgcn_mfma_f32_16x16x32_f16(a2f[s].v, bfm.v, c, 0, 0, 0);
        }
        const float bv = b2s[16*nt + ml];
        #pragma unroll
        for (int r = 0; r < 4; r++) {
            const float v = fmaxf(c[r] + bv, 0.f);
            const float vp = __shfl_xor(v, 1, 64);
            if ((ml & 1) == 0)
                h2w[(q*4 + r)*52 + 8*nt + (ml >> 1)] = f2h_pack(v, vp);
        }
    }
    __syncthreads();

    {
        const int nt = w;
        const uint32* wrow = &w3s[(16*nt + ml)*52];
        f32x4 c = {0.f, 0.f, 0.f, 0.f};
        #pragma unroll
        for (int s = 0; s < 3; s++) {
            HF8 afm, bfm;
            const uint4 ua = *(const uint4*)&h2w[ml*52 + s*16 + q*4];
            afm.u[0] = ua.x; afm.u[1] = ua.y; afm.u[2] = ua.z; afm.u[3] = ua.w;
            const uint4 ub = *(const uint4*)&wrow[s*16 + q*4];
            bfm.u[0] = ub.x; bfm.u[1] = ub.y; bfm.u[2] = ub.z; bfm.u[3] = ub.w;
            c = __builtin_amdgcn_mfma_f32_16x16x32_f16(afm.v, bfm.v, c, 0, 0, 0);
        }
        #pragma unroll
        for (int r = 0; r < 4; r++) {
            float p = c[r] * fuels[(q*4 + r)*68 + 16*nt + ml];
            p += __shfl_xor(p, 1, 64);
            p += __shfl_xor(p, 2, 64);
            p += __shfl_xor(p, 4, 64);
            p += __shfl_xor(p, 8, 64);
            if (ml == 0) part4[w][q*4 + r] = p;
        }
    }
    __syncthreads();

    if (t < 16) out[b0 + t] = part4[0][t] + part4[1][t] + part4[2][t] + part4[3][t];
}

// ---------------------------------------------------------------------------
extern "C" void kernel_launch(void* const* d_in, const int* in_sizes, int n_in,
                              void* d_out, int out_size, void* d_ws, size_t ws_size,
                              hipStream_t stream)
{
    const float* item_emb       = (const float*)d_in[0];
    const float* user_emb       = (const float*)d_in[1];
    const float* W_if           = (const float*)d_in[2];
    const float* b_if           = (const float*)d_in[3];
    const float* W_uf           = (const float*)d_in[4];
    const float* b_uf           = (const float*)d_in[5];
    const float* Wp             = (const float*)d_in[6];
    const float* bp             = (const float*)d_in[7];
    const float* Wf1            = (const float*)d_in[8];
    const float* bf1            = (const float*)d_in[9];
    const float* Wf2            = (const float*)d_in[10];
    const float* bf2            = (const float*)d_in[11];
    const float* Wf3            = (const float*)d_in[12];
    const float* item_features  = (const float*)d_in[13];
    const float* user_features  = (const float*)d_in[14];
    const int*   user_id        = (const int*)d_in[15];
    const int*   target_item_id = (const int*)d_in[16];
    const int*   history_item_id= (const int*)d_in[17];
    const int*   history_len    = (const int*)d_in[18];
    const int*   pos_fb         = (const int*)d_in[19];
    const int*   pos_mask       = (const int*)d_in[20];
    const int*   neg_fb         = (const int*)d_in[21];
    const int*   neg_mask       = (const int*)d_in[22];

    float* out = (float*)d_out;
    float* ws  = (float*)d_ws;

    uint32* IEB  = (uint32*)ws;                       // IV*32
    uint32* WpB  = IEB + (size_t)IV*32;               // NP*32
    uint32* W1B  = WpB + (size_t)NP*32;               // 13312
    uint32* W2B  = W1B + 13312;                       // 8960
    uint32* W3B  = W2B + 8960;                        // 3072
    uint32* PINB = W3B + 3072;                        // BN*32
    float*  FUE  = (float*)(PINB + (size_t)BN*32);
    float*  FIE  = FUE + (size_t)BN*64;
    float*  TP32 = FIE + (size_t)BN*64;               // BN*32
    uint32* TPN  = (uint32*)(TP32 + (size_t)BN*32);   // BN*1568
    float*  PPE  = (float*)(TPN + (size_t)BN*1568);

    k0_cvt<<<dim3(IV*32/256), dim3(256), 0, stream>>>(item_emb, IEB);
    k0b_cvt_wp<<<dim3(13, 32), dim3(256), 0, stream>>>(Wp, WpB);
    k0c_cvt_wf<<<dim3(99), dim3(256), 0, stream>>>(Wf1, Wf2, Wf3, W1B, W2B, W3B);

    k1_gather_attn<<<dim3(BN), dim3(256), 0, stream>>>(
        IEB, item_emb, user_emb, W_if, b_if, W_uf, b_uf,
        item_features, user_features, user_id, target_item_id,
        history_item_id, history_len, pos_fb, pos_mask,
        FUE, FIE, PINB);

    k2_prompt_gemm<<<dim3(25, 64), dim3(256), 0, stream>>>(PINB, WpB, bp, TP32, TPN);

    k3_prompt_mlp<<<dim3(BN), dim3(256), 0, stream>>>(
        IEB, pos_fb, pos_mask, neg_fb, neg_mask, TPN, PPE, out);

    k4_fusion<<<dim3(BN/16), dim3(256), 0, stream>>>(
        FUE, FIE, PPE, TP32, W1B, W2B, W3B, bf1, bf2, out);
}